// Round 5
// baseline (62079.980 us; speedup 1.0000x reference)
//
#include <hip/hip_runtime.h>
#include <stdint.h>

namespace cfg {
// ws layout in FLOAT units
constexpr size_t F_H0   = 0;               // [2][32][512] dec-l0 / enc-fw h (t-parity)
constexpr size_t F_C0   = 32768;           // [32][512]
constexpr size_t F_H1   = 49152;           // [2][32][512] dec-l1 / enc-bw h (t-parity)
constexpr size_t F_C1   = 81920;           // [32][512]
constexpr size_t F_ATTN = 98304;           // [32][512] attention-layer output
constexpr size_t F_VN   = 114688;          // [512] normalized v
constexpr size_t F_CTX  = 115200;          // [32][1024]
constexpr size_t F_EOUT = 147968;          // [32][128][1024] encoder output
constexpr size_t F_KEYS = F_EOUT + 4194304;  // [32][128][512]
constexpr size_t F_TOTAL = F_KEYS + 2097152; // ~25.8 MB
constexpr size_t MEMSET_BYTES = F_VN * 4;    // states + attn zeroed per call
}

__device__ __forceinline__ float sigm(float x)   { return 1.0f / (1.0f + __expf(-x)); }
__device__ __forceinline__ float tanhft(float x) { return 1.0f - 2.0f / (1.0f + __expf(2.0f * x)); }

// stage A-tile [32][KWIN] into LDS
template<int NTH, int KWIN, typename F>
__device__ __forceinline__ void stage(float* at, F&& f) {
  __syncthreads();
  for (int i = threadIdx.x; i < 32 * KWIN; i += NTH) at[i] = f(i / KWIN, i % KWIN);
  __syncthreads();
}

// wave covers one col per lane; waves split KWIN NW ways; accumulate acc[32]
template<int NW, int KWIN, int UNR>
__device__ __forceinline__ void gfrag(const float* __restrict__ W, int ldw,
                                      int col, bool ok, int kw0,
                                      const float* at, float* acc) {
  const int wave = threadIdx.x >> 6;
  constexpr int KQ = KWIN / NW;
  const int klo = wave * KQ;
  const float* wp = W + (size_t)(kw0 + klo) * (size_t)ldw + col;
#pragma unroll 1
  for (int kk = 0; kk < KQ; kk += UNR) {
    float w[UNR];
#pragma unroll
    for (int j = 0; j < UNR; j++) w[j] = ok ? wp[(size_t)j * ldw] : 0.f;
    wp += (size_t)UNR * ldw;
#pragma unroll
    for (int jj = 0; jj < UNR; jj += 4) {
      const float* ap = at + klo + kk + jj;
#pragma unroll
      for (int m = 0; m < 32; m++) {
        float4 a = *(const float4*)(ap + (size_t)m * KWIN);
        acc[m] = fmaf(a.x, w[jj + 0], acc[m]);
        acc[m] = fmaf(a.y, w[jj + 1], acc[m]);
        acc[m] = fmaf(a.z, w[jj + 2], acc[m]);
        acc[m] = fmaf(a.w, w[jj + 3], acc[m]);
      }
    }
  }
}

template<int NW>
__device__ __forceinline__ void redw(float* red, const float* acc) {
  const int wave = threadIdx.x >> 6, lane = threadIdx.x & 63;
  __syncthreads();
#pragma unroll
  for (int m = 0; m < 32; m++) red[(wave * 32 + m) * 64 + lane] = acc[m];
  __syncthreads();
}

template<int NW>
__device__ __forceinline__ float redsum(const float* red, int m, int c) {
  float s = red[m * 64 + c];
#pragma unroll
  for (int w = 1; w < NW; w++) s += red[(w * 32 + m) * 64 + c];
  return s;
}

// ---------------- setup: normalized attention vector ----------------
__global__ __launch_bounds__(256) void k_vnorm(const float* __restrict__ v,
                                               const float* __restrict__ g, float* ws) {
  __shared__ float sh[4];
  const int tid = threadIdx.x, lane = tid & 63, wave = tid >> 6;
  float s = 0.f;
  for (int u = tid; u < 512; u += 256) { float x = v[u]; s = fmaf(x, x, s); }
#pragma unroll
  for (int off = 32; off > 0; off >>= 1) s += __shfl_xor(s, off, 64);
  if (lane == 0) sh[wave] = s;
  __syncthreads();
  float scale = g[0] / sqrtf(sh[0] + sh[1] + sh[2] + sh[3]);
  for (int u = tid; u < 512; u += 256) ws[cfg::F_VN + u] = v[u] * scale;
}

// ---------------- encoder step: gates GEMM + fused activation (both dirs) ----
// grid 64: blocks 0..31 fw (ublk), 32..63 bw. Block owns 16 units x 4 gates,
// full K=1024 -> no cross-block reduction, activation fused in epilogue.
__global__ __launch_bounds__(256) void k_enc(const float* __restrict__ x,
    const int* __restrict__ lens,
    const float* __restrict__ Wfw, const float* __restrict__ bfw,
    const float* __restrict__ Wbw, const float* __restrict__ bbw,
    int t, float* ws) {
  __shared__ float at[4096];   // [32][128]
  __shared__ float red[8192];  // [4][32][64]
  const int tid = threadIdx.x, lane = tid & 63;
  const int dir = blockIdx.x >> 5, ublk = blockIdx.x & 31, U0 = ublk * 16;
  float* H = ws + (dir ? cfg::F_H1 : cfg::F_H0);
  float* C = ws + (dir ? cfg::F_C1 : cfg::F_C0);
  float* eout = ws + cfg::F_EOUT;
  const float* W = dir ? Wbw : Wfw;
  const float* bias = dir ? bbw : bfw;
  const float* hprev = H + (size_t)((t + 1) & 1) * 16384;
  float* hnew = H + (size_t)(t & 1) * 16384;
  const int col = (lane >> 4) * 512 + U0 + (lane & 15);
  float acc[32];
#pragma unroll
  for (int m = 0; m < 32; m++) acc[m] = 0.f;
#pragma unroll 1
  for (int ch = 0; ch < 8; ch++) {
    stage<256, 128>(at, [&](int m, int kl) -> float {
      int kk = ch * 128 + kl;
      if (kk < 512) {
        int tt = t;
        if (dir) { int len = lens[m]; tt = (t < len) ? (len - 1 - t) : t; }
        return x[((size_t)m * 128 + tt) * 512 + kk];
      }
      return hprev[m * 512 + kk - 512];
    });
    gfrag<4, 128, 16>(W, 2048, col, true, ch * 128, at, acc);
  }
  redw<4>(red, acc);
#pragma unroll
  for (int r = 0; r < 2; r++) {
    int q = tid + r * 256;
    int m = q >> 4, ul = q & 15, u = U0 + ul;
    float g4[4];
#pragma unroll
    for (int g = 0; g < 4; g++)
      g4[g] = redsum<4>(red, m, g * 16 + ul) + bias[g * 512 + u];
    int len = lens[m];
    bool valid = t < len;
    float co = C[m * 512 + u];
    float cn = sigm(g4[2] + 1.f) * co + sigm(g4[0]) * tanhft(g4[1]);
    float hn = sigm(g4[3]) * tanhft(cn);
    if (valid) C[m * 512 + u] = cn;
    hnew[m * 512 + u] = valid ? hn : hprev[m * 512 + u];
    int tpos = dir ? (valid ? (len - 1 - t) : t) : t;
    eout[((size_t)m * 128 + tpos) * 1024 + dir * 512 + u] = valid ? hn : 0.f;
  }
}

// ---------------- keys = enc_out @ w_mem ----------------
__global__ __launch_bounds__(256) void k_keys(const float* __restrict__ Wmem, float* ws) {
  __shared__ float at[4096];
  __shared__ float red[8192];
  const int tid = threadIdx.x, lane = tid & 63;
  const int mt = blockIdx.x >> 3, nb = blockIdx.x & 7;
  const float* eout = ws + cfg::F_EOUT;
  float* keys = ws + cfg::F_KEYS;
  const float* arow = eout + (size_t)mt * 32 * 1024;
  const int col = nb * 64 + lane;
  float acc[32];
#pragma unroll
  for (int m = 0; m < 32; m++) acc[m] = 0.f;
#pragma unroll 1
  for (int ch = 0; ch < 8; ch++) {
    stage<256, 128>(at, [&](int m, int kl) -> float {
      return arow[(size_t)m * 1024 + ch * 128 + kl];
    });
    gfrag<4, 128, 16>(Wmem, 512, col, true, ch * 128, at, acc);
  }
  redw<4>(red, acc);
  for (int i = tid; i < 2048; i += 256) {
    int m = i >> 6, nn = i & 63;
    keys[(size_t)mt * 32 * 512 + (size_t)m * 512 + nb * 64 + nn] = redsum<4>(red, m, nn);
  }
}

// ---------------- decoder layer0: gates GEMM + act, K=1536 ----------------
__global__ __launch_bounds__(512) void k_dec0(const float* __restrict__ dec_embed,
    const float* __restrict__ Wd0, const float* __restrict__ bd0, int t, float* ws) {
  __shared__ float at[4096];    // [32][128]
  __shared__ float red[16384];  // [8][32][64]
  const int tid = threadIdx.x, lane = tid & 63;
  const int U0 = blockIdx.x * 16;
  float* H0 = ws + cfg::F_H0;
  float* C0 = ws + cfg::F_C0;
  const float* attn = ws + cfg::F_ATTN;
  const float* hprev = H0 + (size_t)((t + 1) & 1) * 16384;
  float* hnew = H0 + (size_t)(t & 1) * 16384;
  const int col = (lane >> 4) * 512 + U0 + (lane & 15);
  float acc[32];
#pragma unroll
  for (int m = 0; m < 32; m++) acc[m] = 0.f;
#pragma unroll 1
  for (int ch = 0; ch < 12; ch++) {
    stage<512, 128>(at, [&](int m, int kl) -> float {
      int kk = ch * 128 + kl;
      if (kk < 512) return dec_embed[((size_t)m * 128 + t) * 512 + kk];
      if (kk < 1024) return attn[m * 512 + kk - 512];
      return hprev[m * 512 + kk - 1024];
    });
    gfrag<8, 128, 16>(Wd0, 2048, col, true, ch * 128, at, acc);
  }
  redw<8>(red, acc);
  {
    int m = tid >> 4, ul = tid & 15, u = U0 + ul;
    float g4[4];
#pragma unroll
    for (int g = 0; g < 4; g++)
      g4[g] = redsum<8>(red, m, g * 16 + ul) + bd0[g * 512 + u];
    float co = C0[m * 512 + u];
    float cn = sigm(g4[2] + 1.f) * co + sigm(g4[0]) * tanhft(g4[1]);
    float hn = sigm(g4[3]) * tanhft(cn);
    C0[m * 512 + u] = cn;
    hnew[m * 512 + u] = hn;
  }
}

// ---------------- decoder layer1: gates GEMM + act, K=1024 ----------------
__global__ __launch_bounds__(512) void k_dec1(const float* __restrict__ Wd1,
    const float* __restrict__ bd1, int t, float* ws) {
  __shared__ float at[4096];
  __shared__ float red[16384];
  const int tid = threadIdx.x, lane = tid & 63;
  const int U0 = blockIdx.x * 16;
  const float* h0new = ws + cfg::F_H0 + (size_t)(t & 1) * 16384;
  float* H1 = ws + cfg::F_H1;
  float* C1 = ws + cfg::F_C1;
  const float* hprev = H1 + (size_t)((t + 1) & 1) * 16384;
  float* hnew = H1 + (size_t)(t & 1) * 16384;
  const int col = (lane >> 4) * 512 + U0 + (lane & 15);
  float acc[32];
#pragma unroll
  for (int m = 0; m < 32; m++) acc[m] = 0.f;
#pragma unroll 1
  for (int ch = 0; ch < 8; ch++) {
    stage<512, 128>(at, [&](int m, int kl) -> float {
      int kk = ch * 128 + kl;
      return (kk < 512) ? h0new[m * 512 + kk] : hprev[m * 512 + kk - 512];
    });
    gfrag<8, 128, 16>(Wd1, 2048, col, true, ch * 128, at, acc);
  }
  redw<8>(red, acc);
  {
    int m = tid >> 4, ul = tid & 15, u = U0 + ul;
    float g4[4];
#pragma unroll
    for (int g = 0; g < 4; g++)
      g4[g] = redsum<8>(red, m, g * 16 + ul) + bd1[g * 512 + u];
    float co = C1[m * 512 + u];
    float cn = sigm(g4[2] + 1.f) * co + sigm(g4[0]) * tanhft(g4[1]);
    float hn = sigm(g4[3]) * tanhft(cn);
    C1[m * 512 + u] = cn;
    hnew[m * 512 + u] = hn;
  }
}

// ---------------- attention: q-proj, scores, softmax, context (1 block/b) ----
__global__ __launch_bounds__(256) void k_attn(const int* __restrict__ lens,
    const float* __restrict__ Wq, const float* __restrict__ battn,
    int t, float* ws) {
  __shared__ float sm[4096];
  float* sh_h1v = sm;          // 512
  float* sh_qb  = sm + 512;    // 512
  float* sh_vnv = sm + 1024;   // 512
  float* sh_sc  = sm + 1536;   // 128
  float* sh_al  = sm + 1664;   // 128
  float* sh_r   = sm + 1792;   // 16
  float* redq   = sm + 2048;   // 2048
  const int tid = threadIdx.x, lane = tid & 63, wave = tid >> 6;
  const int b = blockIdx.x;
  const int len = lens[b];
  const float* h1 = ws + cfg::F_H1 + (size_t)(t & 1) * 16384 + b * 512;
  const float* vn = ws + cfg::F_VN;
  const float* keys = ws + cfg::F_KEYS + (size_t)b * 128 * 512;
  const float* eo = ws + cfg::F_EOUT + (size_t)b * 128 * 1024;
  float* ctx = ws + cfg::F_CTX + b * 1024;

  for (int u = tid; u < 512; u += 256) { sh_h1v[u] = h1[u]; sh_vnv[u] = vn[u]; }
  __syncthreads();
  // q = h1 @ w_query (waves split K, lanes cover u)
  {
    float4 qa = make_float4(0.f, 0.f, 0.f, 0.f), qb4 = make_float4(0.f, 0.f, 0.f, 0.f);
    const int ua = lane * 4, ub = 256 + lane * 4;
    const float* wqp = Wq + (size_t)(wave * 128) * 512;
#pragma unroll 1
    for (int kk = 0; kk < 128; kk++) {
      float h = sh_h1v[wave * 128 + kk];
      float4 wa = *(const float4*)(wqp + (size_t)kk * 512 + ua);
      float4 wb = *(const float4*)(wqp + (size_t)kk * 512 + ub);
      qa.x = fmaf(h, wa.x, qa.x); qa.y = fmaf(h, wa.y, qa.y);
      qa.z = fmaf(h, wa.z, qa.z); qa.w = fmaf(h, wa.w, qa.w);
      qb4.x = fmaf(h, wb.x, qb4.x); qb4.y = fmaf(h, wb.y, qb4.y);
      qb4.z = fmaf(h, wb.z, qb4.z); qb4.w = fmaf(h, wb.w, qb4.w);
    }
    *(float4*)(redq + wave * 512 + ua) = qa;
    *(float4*)(redq + wave * 512 + ub) = qb4;
  }
  __syncthreads();
  for (int u = tid; u < 512; u += 256)
    sh_qb[u] = redq[u] + redq[512 + u] + redq[1024 + u] + redq[1536 + u] + battn[u];
  __syncthreads();
  // scores
#pragma unroll 1
  for (int tt = 0; tt < 32; tt++) {
    int tq = wave * 32 + tt;
    const float* kp = keys + (size_t)tq * 512;
    float s = 0.f;
#pragma unroll
    for (int hh = 0; hh < 2; hh++) {
      int u = lane * 4 + hh * 256;
      float4 k4 = *(const float4*)(kp + u);
      s += sh_vnv[u + 0] * tanhft(k4.x + sh_qb[u + 0]);
      s += sh_vnv[u + 1] * tanhft(k4.y + sh_qb[u + 1]);
      s += sh_vnv[u + 2] * tanhft(k4.z + sh_qb[u + 2]);
      s += sh_vnv[u + 3] * tanhft(k4.w + sh_qb[u + 3]);
    }
#pragma unroll
    for (int off = 32; off > 0; off >>= 1) s += __shfl_xor(s, off, 64);
    if (lane == 0) sh_sc[tq] = (tq < len) ? s : -1e30f;
  }
  __syncthreads();
  // softmax over 128
  {
    float v = (tid < 128) ? sh_sc[tid] : -1e30f;
    float mx = v;
#pragma unroll
    for (int off = 32; off > 0; off >>= 1) mx = fmaxf(mx, __shfl_xor(mx, off, 64));
    if (lane == 0) sh_r[wave] = mx;
    __syncthreads();
    mx = fmaxf(fmaxf(sh_r[0], sh_r[1]), fmaxf(sh_r[2], sh_r[3]));
    float e = (tid < 128 && tid < len) ? __expf(v - mx) : 0.f;
    float sum = e;
#pragma unroll
    for (int off = 32; off > 0; off >>= 1) sum += __shfl_xor(sum, off, 64);
    if (lane == 0) sh_r[8 + wave] = sum;
    __syncthreads();
    float inv = 1.f / (sh_r[8] + sh_r[9] + sh_r[10] + sh_r[11]);
    if (tid < 128) sh_al[tid] = e * inv;
  }
  __syncthreads();
  // context = alpha @ enc_out[b]
  {
    int d = tid * 4;
    float4 acc = make_float4(0.f, 0.f, 0.f, 0.f);
    const float* ep2 = eo + d;
#pragma unroll 1
    for (int tq = 0; tq < len; tq++) {
      float a = sh_al[tq];
      float4 e4 = *(const float4*)(ep2 + (size_t)tq * 1024);
      acc.x = fmaf(a, e4.x, acc.x); acc.y = fmaf(a, e4.y, acc.y);
      acc.z = fmaf(a, e4.z, acc.z); acc.w = fmaf(a, e4.w, acc.w);
    }
    *(float4*)(ctx + d) = acc;
  }
}

// ---------------- attn vector = (h1|ctx) @ Wal, K=1536 ----------------
__global__ __launch_bounds__(512) void k_wal(const float* __restrict__ Wal,
                                             int t, float* ws) {
  __shared__ float at[4096];
  __shared__ float red[16384];
  const int tid = threadIdx.x, lane = tid & 63;
  const int n0 = blockIdx.x * 64;
  const float* h1 = ws + cfg::F_H1 + (size_t)(t & 1) * 16384;
  const float* ctx = ws + cfg::F_CTX;
  float* attn = ws + cfg::F_ATTN;
  const int col = n0 + lane;
  float acc[32];
#pragma unroll
  for (int m = 0; m < 32; m++) acc[m] = 0.f;
#pragma unroll 1
  for (int ch = 0; ch < 12; ch++) {
    stage<512, 128>(at, [&](int m, int kl) -> float {
      int kk = ch * 128 + kl;
      return (kk < 512) ? h1[m * 512 + kk] : ctx[(size_t)m * 1024 + kk - 512];
    });
    gfrag<8, 128, 16>(Wal, 512, col, true, ch * 128, at, acc);
  }
  redw<8>(red, acc);
  for (int i = tid; i < 2048; i += 512) {
    int m = i >> 6, nn = i & 63;
    attn[(size_t)m * 512 + n0 + nn] = redsum<8>(red, m, nn);
  }
}

// ---------------- projection: logits(t) = attn @ Wproj + bproj ----------------
__global__ __launch_bounds__(256) void k_proj(const float* __restrict__ Wproj,
    const float* __restrict__ bproj, int t, float* __restrict__ out, float* ws) {
  __shared__ float at[4096];
  __shared__ float red[8192];
  const int tid = threadIdx.x, lane = tid & 63;
  const int n0 = blockIdx.x * 64;
  const float* attn = ws + cfg::F_ATTN;
  const int col = n0 + lane;
  const bool ok = col < 9000;
  float acc[32];
#pragma unroll
  for (int m = 0; m < 32; m++) acc[m] = 0.f;
#pragma unroll 1
  for (int ch = 0; ch < 4; ch++) {
    stage<256, 128>(at, [&](int m, int kl) -> float {
      return attn[(size_t)m * 512 + ch * 128 + kl];
    });
    gfrag<4, 128, 16>(Wproj, 9000, col, ok, ch * 128, at, acc);
  }
  redw<4>(red, acc);
  for (int i = tid; i < 2048; i += 256) {
    int m = i >> 6, nn = i & 63;
    int nc = n0 + nn;
    if (nc < 9000)
      out[((size_t)m * 128 + t) * 9000 + nc] = redsum<4>(red, m, nn) + bproj[nc];
  }
}

extern "C" void kernel_launch(void* const* d_in, const int* in_sizes, int n_in,
                              void* d_out, int out_size, void* d_ws, size_t ws_size,
                              hipStream_t stream) {
  (void)in_sizes; (void)n_in; (void)out_size; (void)ws_size;
  const float* embed_in  = (const float*)d_in[0];
  const float* dec_embed = (const float*)d_in[1];
  const int*   lens      = (const int*)d_in[2];
  const float* Wfw = (const float*)d_in[3];  const float* bfw = (const float*)d_in[4];
  const float* Wbw = (const float*)d_in[5];  const float* bbw = (const float*)d_in[6];
  const float* Wd0 = (const float*)d_in[7];  const float* bd0 = (const float*)d_in[8];
  const float* Wd1 = (const float*)d_in[9];  const float* bd1 = (const float*)d_in[10];
  const float* Wmem = (const float*)d_in[11];
  const float* Wq   = (const float*)d_in[12];
  const float* battn = (const float*)d_in[13];
  const float* vattn = (const float*)d_in[14];
  const float* gattn = (const float*)d_in[15];
  const float* Wal   = (const float*)d_in[16];
  const float* Wproj = (const float*)d_in[17];
  const float* bproj = (const float*)d_in[18];
  float* out = (float*)d_out;
  float* ws  = (float*)d_ws;

  hipMemsetAsync(d_ws, 0, cfg::MEMSET_BYTES, stream);  // states + attn = 0
  hipLaunchKernelGGL(k_vnorm, dim3(1), dim3(256), 0, stream, vattn, gattn, ws);

  for (int t = 0; t < 128; t++)
    hipLaunchKernelGGL(k_enc, dim3(64), dim3(256), 0, stream,
                       embed_in, lens, Wfw, bfw, Wbw, bbw, t, ws);

  hipLaunchKernelGGL(k_keys, dim3(1024), dim3(256), 0, stream, Wmem, ws);

  for (int t = 0; t < 128; t++) {
    hipLaunchKernelGGL(k_dec0, dim3(32), dim3(512), 0, stream, dec_embed, Wd0, bd0, t, ws);
    hipLaunchKernelGGL(k_dec1, dim3(32), dim3(512), 0, stream, Wd1, bd1, t, ws);
    hipLaunchKernelGGL(k_attn, dim3(32), dim3(256), 0, stream, lens, Wq, battn, t, ws);
    hipLaunchKernelGGL(k_wal, dim3(8), dim3(512), 0, stream, Wal, t, ws);
    hipLaunchKernelGGL(k_proj, dim3(141), dim3(256), 0, stream, Wproj, bproj, t, out, ws);
  }
}

// Round 6
// 50660.007 us; speedup vs baseline: 1.2254x; 1.2254x over previous
//
#include <hip/hip_runtime.h>
#include <stdint.h>

#define NTHR 256
#define NBLKS 192

typedef unsigned long long ull;

namespace cfg {
// ws layout in FLOAT units
constexpr size_t F_H0    = 32768;             // [2][32][512] (t-parity)
constexpr size_t F_C0    = F_H0 + 32768;      // [32][512]
constexpr size_t F_H1    = F_C0 + 16384;      // [2][32][512]
constexpr size_t F_C1    = F_H1 + 32768;      // [32][512]
constexpr size_t F_ATTNS = F_C1 + 16384;      // [2][32][512] attn vector (parity dbuf)
constexpr size_t F_VN    = F_ATTNS + 32768;   // [512]
constexpr size_t F_CTX   = F_VN + 512;        // [32][1024]
constexpr size_t F_EOUT  = F_CTX + 32768;     // [32][128][1024] (write-once)
constexpr size_t F_KEYS  = F_EOUT + 4194304;  // [32][128][512]  (write-once)
constexpr size_t F_TOTAL = F_KEYS + 2097152;  // ~26 MB
constexpr size_t MEMSET_BYTES = F_VN * 4;     // cells + states + attn_s
}

__device__ __forceinline__ float sigm(float x)   { return 1.0f / (1.0f + __expf(-x)); }
__device__ __forceinline__ float tanhft(float x) { return 1.0f - 2.0f / (1.0f + __expf(2.0f * x)); }

// agent-coherent access (coherence point; safe across non-coherent XCD L2s)
__device__ __forceinline__ float cload(const float* p) {
  return __hip_atomic_load(p, __ATOMIC_RELAXED, __HIP_MEMORY_SCOPE_AGENT);
}
__device__ __forceinline__ void cstore(float* p, float v) {
  __hip_atomic_store(p, v, __ATOMIC_RELAXED, __HIP_MEMORY_SCOPE_AGENT);
}
__device__ __forceinline__ ull cload64(const float* p) {
  return __hip_atomic_load((const ull*)p, __ATOMIC_RELAXED, __HIP_MEMORY_SCOPE_AGENT);
}

// checker/broadcast grid barrier, s_sleep backoff
__device__ __forceinline__ void gbar(unsigned ep, unsigned* arr, unsigned* rel) {
  __syncthreads();
  if (blockIdx.x == 0) {
    if (threadIdx.x == 0)
      __hip_atomic_store(arr, ep, __ATOMIC_RELAXED, __HIP_MEMORY_SCOPE_AGENT);
    if (threadIdx.x < NBLKS)
      while (__hip_atomic_load(arr + threadIdx.x, __ATOMIC_RELAXED, __HIP_MEMORY_SCOPE_AGENT) < ep)
        __builtin_amdgcn_s_sleep(8);
    __syncthreads();
    if (threadIdx.x < NBLKS)
      __hip_atomic_store(rel + (size_t)threadIdx.x * 32, ep, __ATOMIC_RELAXED, __HIP_MEMORY_SCOPE_AGENT);
    __syncthreads();
  } else {
    if (threadIdx.x == 0) {
      __hip_atomic_store(arr + blockIdx.x, ep, __ATOMIC_RELAXED, __HIP_MEMORY_SCOPE_AGENT);
      while (__hip_atomic_load(rel + (size_t)blockIdx.x * 32, __ATOMIC_RELAXED,
                               __HIP_MEMORY_SCOPE_AGENT) < ep)
        __builtin_amdgcn_s_sleep(16);
    }
    __syncthreads();
  }
}

// GEMM over one staged K-chunk of 128: waves split rows (32 each), lane = 1 col.
template<int UNR, bool NT>
__device__ __forceinline__ void gemm_chunk(const float* __restrict__ W, int ldw,
                                           int col, bool ok, int kbase,
                                           const float* at, float* acc) {
  const int wave = threadIdx.x >> 6;
  const float* wp = W + (size_t)(kbase + wave * 32) * (size_t)ldw + col;
  const float* ap0 = at + wave * 32;
#pragma unroll 1
  for (int kk = 0; kk < 32; kk += UNR) {
    float w[UNR];
#pragma unroll
    for (int j = 0; j < UNR; j++)
      w[j] = ok ? (NT ? __builtin_nontemporal_load(wp + (size_t)j * ldw)
                      : wp[(size_t)j * ldw])
                : 0.f;
    wp += (size_t)UNR * ldw;
#pragma unroll
    for (int jj = 0; jj < UNR; jj += 4) {
      const float* ap = ap0 + kk + jj;
#pragma unroll
      for (int m = 0; m < 32; m++) {
        float4 a = *(const float4*)(ap + m * 128);
        acc[m] = fmaf(a.x, w[jj + 0], acc[m]);
        acc[m] = fmaf(a.y, w[jj + 1], acc[m]);
        acc[m] = fmaf(a.z, w[jj + 2], acc[m]);
        acc[m] = fmaf(a.w, w[jj + 3], acc[m]);
      }
    }
  }
}

// red layout [4][32][64] = 8192 floats
__device__ __forceinline__ void redw(float* red, const float* acc) {
  const int wave = threadIdx.x >> 6, lane = threadIdx.x & 63;
  __syncthreads();
#pragma unroll
  for (int m = 0; m < 32; m++) red[(wave * 32 + m) * 64 + lane] = acc[m];
  __syncthreads();
}
__device__ __forceinline__ float redsum(const float* red, int m, int c) {
  return red[m * 64 + c] + red[2048 + m * 64 + c] +
         red[4096 + m * 64 + c] + red[6144 + m * 64 + c];
}

__global__ __launch_bounds__(NTHR) void seq2seq_kernel(
    const float* __restrict__ embed_in, const float* __restrict__ dec_embed,
    const int* __restrict__ lens,
    const float* __restrict__ Wfw, const float* __restrict__ bfw,
    const float* __restrict__ Wbw, const float* __restrict__ bbw,
    const float* __restrict__ Wd0, const float* __restrict__ bd0,
    const float* __restrict__ Wd1, const float* __restrict__ bd1,
    const float* __restrict__ Wmem, const float* __restrict__ Wq,
    const float* __restrict__ battn, const float* __restrict__ vattn,
    const float* __restrict__ gattn, const float* __restrict__ Wal,
    const float* __restrict__ Wproj, const float* __restrict__ bproj,
    float* __restrict__ out, float* ws) {
  __shared__ float at[4096];   // [32][128] staged chunk (attn phase reuses)
  __shared__ float red[8192];  // [4][32][64]

  unsigned* arr = (unsigned*)ws;        // [192]
  unsigned* rel = (unsigned*)ws + 512;  // [192*32]
  float* H0     = ws + cfg::F_H0;       // 2 parities
  float* C0     = ws + cfg::F_C0;
  float* H1     = ws + cfg::F_H1;
  float* C1     = ws + cfg::F_C1;
  float* attn_s = ws + cfg::F_ATTNS;    // parity stride 16384
  float* vn     = ws + cfg::F_VN;
  float* ctx    = ws + cfg::F_CTX;
  float* eout   = ws + cfg::F_EOUT;
  float* keysp  = ws + cfg::F_KEYS;

  const int bid = blockIdx.x, tid = threadIdx.x;
  const int wave = tid >> 6, lane = tid & 63;
  unsigned ep = 1;
#define BAR()  do { gbar(ep, arr, rel); ep++; } while (0)
#define BARSEAL() do { __threadfence(); gbar(ep, arr, rel); ep++; __threadfence(); } while (0)

  // ---------------- setup: normalized attention vector (block 0) ----------------
  if (bid == 0) {
    float s = 0.f;
    for (int u = tid; u < 512; u += NTHR) { float x = vattn[u]; s = fmaf(x, x, s); }
#pragma unroll
    for (int off = 32; off > 0; off >>= 1) s += __shfl_xor(s, off, 64);
    __syncthreads();
    if (lane == 0) at[wave] = s;
    __syncthreads();
    float scale = gattn[0] / sqrtf(at[0] + at[1] + at[2] + at[3]);
    for (int u = tid; u < 512; u += NTHR) vn[u] = vattn[u] * scale;  // sealed later
    __syncthreads();
  }

  // ---------------- encoder: 1 fused phase/step, 64 blocks ----------------
  for (int t = 0; t < 128; t++) {
    if (bid < 64) {
      const int dir = bid >> 5, U0 = (bid & 31) * 16;
      const float* W = dir ? Wbw : Wfw;
      const float* bias = dir ? bbw : bfw;
      float* H = dir ? H1 : H0;
      float* C = dir ? C1 : C0;
      const float* hprev = H + (size_t)((t + 1) & 1) * 16384;
      float* hnew = H + (size_t)(t & 1) * 16384;
      const int col = (lane >> 4) * 512 + U0 + (lane & 15);  // gate*512 + unit
      float acc[32];
#pragma unroll
      for (int m = 0; m < 32; m++) acc[m] = 0.f;
#pragma unroll 1
      for (int ch = 0; ch < 8; ch++) {
        __syncthreads();
        if (ch < 4) {
          for (int i = tid; i < 1024; i += NTHR) {
            int m = i >> 5, k4 = i & 31;
            int tt = t;
            if (dir) { int len = lens[m]; tt = (t < len) ? (len - 1 - t) : t; }
            *(float4*)&at[m * 128 + k4 * 4] =
                *(const float4*)&embed_in[((size_t)m * 128 + tt) * 512 + ch * 128 + k4 * 4];
          }
        } else {
          for (int i = tid; i < 2048; i += NTHR) {
            int m = i >> 6, k2 = i & 63;
            *(ull*)&at[m * 128 + k2 * 2] = cload64(hprev + m * 512 + (ch - 4) * 128 + k2 * 2);
          }
        }
        __syncthreads();
        gemm_chunk<16, false>(W, 2048, col, true, ch * 128, at, acc);
      }
      redw(red, acc);
#pragma unroll
      for (int r = 0; r < 2; r++) {
        int idx = tid + r * 256;  // 512 items: (m, ul)
        int m = idx >> 4, ul = idx & 15, u = U0 + ul;
        float g4[4];
#pragma unroll
        for (int g = 0; g < 4; g++) g4[g] = redsum(red, m, g * 16 + ul) + bias[g * 512 + u];
        int len = lens[m];
        bool valid = t < len;
        float co = C[m * 512 + u];  // block-private: plain
        float cn = sigm(g4[2] + 1.f) * co + sigm(g4[0]) * tanhft(g4[1]);
        float hn = sigm(g4[3]) * tanhft(cn);
        if (valid) C[m * 512 + u] = cn;
        cstore(hnew + m * 512 + u, valid ? hn : cload(hprev + m * 512 + u));
        int tpos = dir ? (valid ? (len - 1 - t) : t) : t;
        eout[((size_t)m * 128 + tpos) * 1024 + dir * 512 + u] = valid ? hn : 0.f;  // sealed
      }
    }
    BAR();
  }
  BARSEAL();  // seal eout + vn

  // ---------------- keys = enc_out @ w_mem (1024 tasks over 192 blocks) ----------------
#pragma unroll 1
  for (int task = bid; task < 1024; task += NBLKS) {
    int mt = task >> 3, nb = task & 7;
    const float* arow = eout + (size_t)mt * 32 * 1024;
    const int col = nb * 64 + lane;
    float acc[32];
#pragma unroll
    for (int m = 0; m < 32; m++) acc[m] = 0.f;
#pragma unroll 1
    for (int ch = 0; ch < 8; ch++) {
      __syncthreads();
      for (int i = tid; i < 1024; i += NTHR) {
        int m = i >> 5, k4 = i & 31;
        *(float4*)&at[m * 128 + k4 * 4] =
            *(const float4*)&arow[(size_t)m * 1024 + ch * 128 + k4 * 4];
      }
      __syncthreads();
      gemm_chunk<16, false>(Wmem, 512, col, true, ch * 128, at, acc);
    }
    redw(red, acc);
    for (int i = tid; i < 2048; i += NTHR) {
      int m = i >> 6, nn = i & 63;
      keysp[(size_t)mt * 32 * 512 + (size_t)m * 512 + nb * 64 + nn] = redsum(red, m, nn);
    }
  }
  BARSEAL();  // seal keys

  // ---------------- decoder: 4 phases/step ----------------
  for (int t = 0; t < 128; t++) {
    // P1: dec0 fused (blocks 0..31) || proj(t-1) (blocks 48..188, nt W loads)
    if (bid < 32) {
      const int U0 = bid * 16;
      const float* asrc = attn_s + (size_t)((t + 1) & 1) * 16384;  // attn(t-1)
      const float* hprev = H0 + (size_t)((t + 1) & 1) * 16384;
      float* hnew = H0 + (size_t)(t & 1) * 16384;
      const int col = (lane >> 4) * 512 + U0 + (lane & 15);
      float acc[32];
#pragma unroll
      for (int m = 0; m < 32; m++) acc[m] = 0.f;
#pragma unroll 1
      for (int ch = 0; ch < 12; ch++) {
        __syncthreads();
        if (ch < 4) {
          for (int i = tid; i < 1024; i += NTHR) {
            int m = i >> 5, k4 = i & 31;
            *(float4*)&at[m * 128 + k4 * 4] =
                *(const float4*)&dec_embed[((size_t)m * 128 + t) * 512 + ch * 128 + k4 * 4];
          }
        } else {
          const float* src = (ch < 8) ? asrc : hprev;
          int cc = (ch < 8) ? (ch - 4) : (ch - 8);
          for (int i = tid; i < 2048; i += NTHR) {
            int m = i >> 6, k2 = i & 63;
            *(ull*)&at[m * 128 + k2 * 2] = cload64(src + m * 512 + cc * 128 + k2 * 2);
          }
        }
        __syncthreads();
        gemm_chunk<16, false>(Wd0, 2048, col, true, ch * 128, at, acc);
      }
      redw(red, acc);
#pragma unroll
      for (int r = 0; r < 2; r++) {
        int idx = tid + r * 256;
        int m = idx >> 4, ul = idx & 15, u = U0 + ul;
        float g4[4];
#pragma unroll
        for (int g = 0; g < 4; g++) g4[g] = redsum(red, m, g * 16 + ul) + bd0[g * 512 + u];
        float co = C0[m * 512 + u];
        float cn = sigm(g4[2] + 1.f) * co + sigm(g4[0]) * tanhft(g4[1]);
        float hn = sigm(g4[3]) * tanhft(cn);
        C0[m * 512 + u] = cn;
        cstore(hnew + m * 512 + u, hn);
      }
    } else if (bid >= 48 && bid < 189 && t >= 1) {
      int n0 = (bid - 48) * 64;
      const float* asrc = attn_s + (size_t)((t + 1) & 1) * 16384;  // attn(t-1)
      const int col = n0 + lane;
      const bool ok = col < 9000;
      float acc[32];
#pragma unroll
      for (int m = 0; m < 32; m++) acc[m] = 0.f;
#pragma unroll 1
      for (int ch = 0; ch < 4; ch++) {
        __syncthreads();
        for (int i = tid; i < 2048; i += NTHR) {
          int m = i >> 6, k2 = i & 63;
          *(ull*)&at[m * 128 + k2 * 2] = cload64(asrc + m * 512 + ch * 128 + k2 * 2);
        }
        __syncthreads();
        gemm_chunk<32, true>(Wproj, 9000, col, ok, ch * 128, at, acc);
      }
      redw(red, acc);
      for (int i = tid; i < 2048; i += NTHR) {
        int m = i >> 6, nn = i & 63;
        int nc = n0 + nn;
        if (nc < 9000)
          out[((size_t)m * 128 + (t - 1)) * 9000 + nc] = redsum(red, m, nn) + bproj[nc];
      }
    }
    BAR();

    // P2: dec1 fused (blocks 32..63)
    if (bid >= 32 && bid < 64) {
      const int U0 = (bid - 32) * 16;
      const float* h0new = H0 + (size_t)(t & 1) * 16384;
      const float* hprev = H1 + (size_t)((t + 1) & 1) * 16384;
      float* hnew = H1 + (size_t)(t & 1) * 16384;
      const int col = (lane >> 4) * 512 + U0 + (lane & 15);
      float acc[32];
#pragma unroll
      for (int m = 0; m < 32; m++) acc[m] = 0.f;
#pragma unroll 1
      for (int ch = 0; ch < 8; ch++) {
        __syncthreads();
        const float* src = (ch < 4) ? h0new : hprev;
        int cc = ch & 3;
        for (int i = tid; i < 2048; i += NTHR) {
          int m = i >> 6, k2 = i & 63;
          *(ull*)&at[m * 128 + k2 * 2] = cload64(src + m * 512 + cc * 128 + k2 * 2);
        }
        __syncthreads();
        gemm_chunk<16, false>(Wd1, 2048, col, true, ch * 128, at, acc);
      }
      redw(red, acc);
#pragma unroll
      for (int r = 0; r < 2; r++) {
        int idx = tid + r * 256;
        int m = idx >> 4, ul = idx & 15, u = U0 + ul;
        float g4[4];
#pragma unroll
        for (int g = 0; g < 4; g++) g4[g] = redsum(red, m, g * 16 + ul) + bd1[g * 512 + u];
        float co = C1[m * 512 + u];
        float cn = sigm(g4[2] + 1.f) * co + sigm(g4[0]) * tanhft(g4[1]);
        float hn = sigm(g4[3]) * tanhft(cn);
        C1[m * 512 + u] = cn;
        cstore(hnew + m * 512 + u, hn);
      }
    }
    BAR();

    // P3: attention (blocks 0..31) + zero attn_s[t&1] (blocks 64..79)
    if (bid < 32) {
      const int b = bid;
      const int len = lens[b];
      float* sh_h1v = at;          // 512
      float* sh_qb  = at + 512;    // 512
      float* sh_vnv = at + 1024;   // 512
      float* sh_sc  = at + 1536;   // 128
      float* sh_al  = at + 1664;   // 128
      float* sh_r   = at + 1792;   // 16
      float* redq   = at + 2048;   // 2048
      const float* h1 = H1 + (size_t)(t & 1) * 16384 + b * 512;
      const float* keys = keysp + (size_t)b * 128 * 512;
      const float* eo = eout + (size_t)b * 128 * 1024;
      __syncthreads();
      { int u2 = tid * 2; *(ull*)&sh_h1v[u2] = cload64(h1 + u2); }
      for (int u = tid; u < 512; u += NTHR) sh_vnv[u] = vn[u];
      __syncthreads();
      {  // q = h1 @ w_query
        float4 qa = make_float4(0.f, 0.f, 0.f, 0.f), qb4 = make_float4(0.f, 0.f, 0.f, 0.f);
        const int ua = lane * 4, ub = 256 + lane * 4;
        const float* wqp = Wq + (size_t)(wave * 128) * 512;
#pragma unroll 1
        for (int kk = 0; kk < 128; kk++) {
          float h = sh_h1v[wave * 128 + kk];
          float4 wa = *(const float4*)(wqp + (size_t)kk * 512 + ua);
          float4 wb = *(const float4*)(wqp + (size_t)kk * 512 + ub);
          qa.x = fmaf(h, wa.x, qa.x); qa.y = fmaf(h, wa.y, qa.y);
          qa.z = fmaf(h, wa.z, qa.z); qa.w = fmaf(h, wa.w, qa.w);
          qb4.x = fmaf(h, wb.x, qb4.x); qb4.y = fmaf(h, wb.y, qb4.y);
          qb4.z = fmaf(h, wb.z, qb4.z); qb4.w = fmaf(h, wb.w, qb4.w);
        }
        *(float4*)(redq + wave * 512 + ua) = qa;
        *(float4*)(redq + wave * 512 + ub) = qb4;
      }
      __syncthreads();
      for (int u = tid; u < 512; u += NTHR)
        sh_qb[u] = redq[u] + redq[512 + u] + redq[1024 + u] + redq[1536 + u] + battn[u];
      __syncthreads();
#pragma unroll 1
      for (int tt = 0; tt < 32; tt++) {  // scores
        int tq = wave * 32 + tt;
        const float* kp = keys + (size_t)tq * 512;
        float s = 0.f;
#pragma unroll
        for (int hh = 0; hh < 2; hh++) {
          int u = lane * 4 + hh * 256;
          float4 k4 = *(const float4*)(kp + u);
          s += sh_vnv[u + 0] * tanhft(k4.x + sh_qb[u + 0]);
          s += sh_vnv[u + 1] * tanhft(k4.y + sh_qb[u + 1]);
          s += sh_vnv[u + 2] * tanhft(k4.z + sh_qb[u + 2]);
          s += sh_vnv[u + 3] * tanhft(k4.w + sh_qb[u + 3]);
        }
#pragma unroll
        for (int off = 32; off > 0; off >>= 1) s += __shfl_xor(s, off, 64);
        if (lane == 0) sh_sc[tq] = (tq < len) ? s : -1e30f;
      }
      __syncthreads();
      {  // softmax over 128
        float v = (tid < 128) ? sh_sc[tid] : -1e30f;
        float mx = v;
#pragma unroll
        for (int off = 32; off > 0; off >>= 1) mx = fmaxf(mx, __shfl_xor(mx, off, 64));
        if (lane == 0) sh_r[wave] = mx;
        __syncthreads();
        mx = fmaxf(fmaxf(sh_r[0], sh_r[1]), fmaxf(sh_r[2], sh_r[3]));
        float e = (tid < 128 && tid < len) ? __expf(v - mx) : 0.f;
        float sum = e;
#pragma unroll
        for (int off = 32; off > 0; off >>= 1) sum += __shfl_xor(sum, off, 64);
        if (lane == 0) sh_r[8 + wave] = sum;
        __syncthreads();
        float inv = 1.f / (sh_r[8] + sh_r[9] + sh_r[10] + sh_r[11]);
        if (tid < 128) sh_al[tid] = e * inv;
      }
      __syncthreads();
      {  // context
        int d = tid * 4;
        float4 acc = make_float4(0.f, 0.f, 0.f, 0.f);
        const float* ep2 = eo + d;
#pragma unroll 1
        for (int tq = 0; tq < len; tq++) {
          float a = sh_al[tq];
          float4 e4 = *(const float4*)(ep2 + (size_t)tq * 1024);
          acc.x = fmaf(a, e4.x, acc.x); acc.y = fmaf(a, e4.y, acc.y);
          acc.z = fmaf(a, e4.z, acc.z); acc.w = fmaf(a, e4.w, acc.w);
        }
        float* cp = ctx + b * 1024 + d;
        cstore(cp + 0, acc.x); cstore(cp + 1, acc.y);
        cstore(cp + 2, acc.z); cstore(cp + 3, acc.w);
      }
    } else if (bid >= 64 && bid < 80) {
      float* az = attn_s + (size_t)(t & 1) * 16384 + (size_t)(bid - 64) * 2048;
      for (int i = tid; i < 2048; i += NTHR) cstore(az + i, 0.f);
    }
    BAR();

    // P4: attn(t) = (h1|ctx) @ Wal, K-split 4 x 8 nb (blocks 64..95), atomicAdd
    if (bid >= 64 && bid < 96) {
      const int wb = bid - 64, kb = wb >> 3, nb = wb & 7;
      const float* h1v = H1 + (size_t)(t & 1) * 16384;
      const int col = nb * 64 + lane;
      float acc[32];
#pragma unroll
      for (int m = 0; m < 32; m++) acc[m] = 0.f;
#pragma unroll 1
      for (int ch = 0; ch < 3; ch++) {
        __syncthreads();
        for (int i = tid; i < 2048; i += NTHR) {
          int m = i >> 6, k2 = i & 63;
          int kk = kb * 384 + ch * 128 + k2 * 2;
          const float* src = (kk < 512) ? (h1v + m * 512 + kk) : (ctx + (size_t)m * 1024 + kk - 512);
          *(ull*)&at[m * 128 + k2 * 2] = cload64(src);
        }
        __syncthreads();
        gemm_chunk<16, false>(Wal, 512, col, true, kb * 384 + ch * 128, at, acc);
      }
      redw(red, acc);
      float* adst = attn_s + (size_t)(t & 1) * 16384;
      for (int i = tid; i < 2048; i += NTHR) {
        int m = i >> 6, nn = i & 63;
        atomicAdd(adst + (size_t)m * 512 + nb * 64 + nn, redsum(red, m, nn));
      }
    }
    BAR();
  }

  // trailing projection for t=127
  if (bid >= 48 && bid < 189) {
    int n0 = (bid - 48) * 64;
    const float* asrc = attn_s + (size_t)(127 & 1) * 16384;  // attn(127)
    const int col = n0 + lane;
    const bool ok = col < 9000;
    float acc[32];
#pragma unroll
    for (int m = 0; m < 32; m++) acc[m] = 0.f;
#pragma unroll 1
    for (int ch = 0; ch < 4; ch++) {
      __syncthreads();
      for (int i = tid; i < 2048; i += NTHR) {
        int m = i >> 6, k2 = i & 63;
        *(ull*)&at[m * 128 + k2 * 2] = cload64(asrc + m * 512 + ch * 128 + k2 * 2);
      }
      __syncthreads();
      gemm_chunk<32, true>(Wproj, 9000, col, ok, ch * 128, at, acc);
    }
    redw(red, acc);
    for (int i = tid; i < 2048; i += NTHR) {
      int m = i >> 6, nn = i & 63;
      int nc = n0 + nn;
      if (nc < 9000)
        out[((size_t)m * 128 + 127) * 9000 + nc] = redsum(red, m, nn) + bproj[nc];
    }
  }
#undef BAR
#undef BARSEAL
}

extern "C" void kernel_launch(void* const* d_in, const int* in_sizes, int n_in,
                              void* d_out, int out_size, void* d_ws, size_t ws_size,
                              hipStream_t stream) {
  (void)in_sizes; (void)n_in; (void)out_size; (void)ws_size;
  hipMemsetAsync(d_ws, 0, cfg::MEMSET_BYTES, stream);  // cells + states + attn_s
  hipLaunchKernelGGL(seq2seq_kernel, dim3(NBLKS), dim3(NTHR), 0, stream,
                     (const float*)d_in[0],   // embed_in
                     (const float*)d_in[1],   // dec_embed
                     (const int*)d_in[2],     // in_seq_len
                     (const float*)d_in[3],   // enc_fw_kernel
                     (const float*)d_in[4],   // enc_fw_bias
                     (const float*)d_in[5],   // enc_bw_kernel
                     (const float*)d_in[6],   // enc_bw_bias
                     (const float*)d_in[7],   // dec_kernel0
                     (const float*)d_in[8],   // dec_bias0
                     (const float*)d_in[9],   // dec_kernel1
                     (const float*)d_in[10],  // dec_bias1
                     (const float*)d_in[11],  // w_mem
                     (const float*)d_in[12],  // w_query
                     (const float*)d_in[13],  // b_attn
                     (const float*)d_in[14],  // v_attn
                     (const float*)d_in[15],  // g_attn
                     (const float*)d_in[16],  // w_attn_layer
                     (const float*)d_in[17],  // w_proj
                     (const float*)d_in[18],  // b_proj
                     (float*)d_out, (float*)d_ws);
}

// Round 9
// 29861.038 us; speedup vs baseline: 2.0790x; 1.6965x over previous
//
#include <hip/hip_runtime.h>
#include <stdint.h>

#define NTHR 256
#define NBLKS 512

namespace cfg {
// ws layout in FLOAT units (identical to round 4 — proven)
constexpr size_t F_CELLS = 0;                     // arr[512] u32 + rel[512*32] u32
constexpr size_t F_H0    = 524288;                // [32][512]
constexpr size_t F_C0    = F_H0 + 16384;
constexpr size_t F_H1    = F_C0 + 16384;
constexpr size_t F_C1    = F_H1 + 16384;
constexpr size_t F_ATTNS = F_C1 + 16384;          // [2][32][512] attn vector (parity dbuf)
constexpr size_t F_VN    = F_ATTNS + 32768;       // [512]
constexpr size_t F_CTX   = F_VN + 512;            // [32][1024]
constexpr size_t F_P0    = F_CTX + 32768;         // [16][32][2048] gate partials
constexpr size_t F_P1    = F_P0 + 1048576;        // [16][32][2048]
constexpr size_t F_EOUT  = F_P1 + 1048576;        // [32][128][1024] (write-once)
constexpr size_t F_KEYS  = F_EOUT + 4194304;      // [32][128][512]  (write-once)
constexpr size_t F_TOTAL = F_KEYS + 2097152;      // ~36.2 MB (proven budget)
constexpr size_t MEMSET_BYTES = F_VN * 4;         // cells + states + attn_s
}

__device__ __forceinline__ float sigm(float x)   { return 1.0f / (1.0f + __expf(-x)); }
__device__ __forceinline__ float tanhft(float x) { return 1.0f - 2.0f / (1.0f + __expf(2.0f * x)); }

// 32-bit agent-scope access — the ONLY uncached primitive (R4-proven)
__device__ __forceinline__ float cload(const float* p) {
  return __hip_atomic_load(p, __ATOMIC_RELAXED, __HIP_MEMORY_SCOPE_AGENT);
}
__device__ __forceinline__ void cstore(float* p, float v) {
  __hip_atomic_store(p, v, __ATOMIC_RELAXED, __HIP_MEMORY_SCOPE_AGENT);
}

// checker/broadcast grid barrier (R4-proven, unchanged)
__device__ __forceinline__ void gbar(unsigned ep, unsigned* arr, unsigned* rel) {
  __syncthreads();
  if (blockIdx.x == 0) {
    if (threadIdx.x == 0)
      __hip_atomic_store(arr, ep, __ATOMIC_RELAXED, __HIP_MEMORY_SCOPE_AGENT);
    int s0 = threadIdx.x, s1 = threadIdx.x + 256;
    while (__hip_atomic_load(arr + s0, __ATOMIC_RELAXED, __HIP_MEMORY_SCOPE_AGENT) < ep)
      __builtin_amdgcn_s_sleep(1);
    while (__hip_atomic_load(arr + s1, __ATOMIC_RELAXED, __HIP_MEMORY_SCOPE_AGENT) < ep)
      __builtin_amdgcn_s_sleep(1);
    __syncthreads();
    __hip_atomic_store(rel + (size_t)s0 * 32, ep, __ATOMIC_RELAXED, __HIP_MEMORY_SCOPE_AGENT);
    __hip_atomic_store(rel + (size_t)s1 * 32, ep, __ATOMIC_RELAXED, __HIP_MEMORY_SCOPE_AGENT);
    __syncthreads();
  } else {
    if (threadIdx.x == 0) {
      __hip_atomic_store(arr + blockIdx.x, ep, __ATOMIC_RELAXED, __HIP_MEMORY_SCOPE_AGENT);
      while (__hip_atomic_load(rel + (size_t)blockIdx.x * 32, __ATOMIC_RELAXED,
                               __HIP_MEMORY_SCOPE_AGENT) < ep)
        __builtin_amdgcn_s_sleep(1);
    }
    __syncthreads();
  }
}

// stage A-tile [32][KWIN] into LDS — BATCHED: gather all elems into registers
// (loads issue back-to-back), then write LDS. Only change vs R4's stage().
template<int KWIN, typename F>
__device__ __forceinline__ void stage(float* at, F&& f) {
  static_assert((32 * KWIN) % NTHR == 0, "tile must tile NTHR");
  constexpr int PER = (32 * KWIN) / NTHR;
  __syncthreads();
  float v[PER];
#pragma unroll
  for (int r = 0; r < PER; r++) {
    int i = threadIdx.x + NTHR * r;
    v[r] = f(i / KWIN, i % KWIN);
  }
#pragma unroll
  for (int r = 0; r < PER; r++) at[threadIdx.x + NTHR * r] = v[r];
  __syncthreads();
}

// accumulate into caller-owned acc[32]; wave covers 64 n-cols, K-chunk KWIN/4 (R4-proven)
template<int KWIN, int UNR>
__device__ __forceinline__ void gemm_frag(const float* __restrict__ W, int ldw,
                                          int n, bool nok, int kw0,
                                          const float* at, float* acc) {
  const int wave = threadIdx.x >> 6;
  constexpr int KQ = KWIN / 4;
  const int klo = wave * KQ;
  const float* wp = W + (size_t)(kw0 + klo) * (size_t)ldw + n;
#pragma unroll 1
  for (int kk = 0; kk < KQ; kk += UNR) {
    float w[UNR];
#pragma unroll
    for (int j = 0; j < UNR; j++) w[j] = nok ? wp[(size_t)j * ldw] : 0.f;
    wp += (size_t)UNR * ldw;
#pragma unroll
    for (int jj = 0; jj < UNR; jj += 4) {
      const float* ap = at + klo + kk + jj;
#pragma unroll
      for (int m = 0; m < 32; m++) {
        float4 a = *(const float4*)(ap + m * KWIN);
        acc[m] = fmaf(a.x, w[jj + 0], acc[m]);
        acc[m] = fmaf(a.y, w[jj + 1], acc[m]);
        acc[m] = fmaf(a.z, w[jj + 2], acc[m]);
        acc[m] = fmaf(a.w, w[jj + 3], acc[m]);
      }
    }
  }
}

// red layout [4][32][64] = 8192 floats (R4-proven)
__device__ __forceinline__ void red_write(float* red, const float* acc) {
  const int wave = threadIdx.x >> 6, lane = threadIdx.x & 63;
  __syncthreads();
#pragma unroll
  for (int m = 0; m < 32; m++) red[(wave * 32 + m) * 64 + lane] = acc[m];
  __syncthreads();
}

__device__ __forceinline__ void epi_cstore(const float* red, float* outp, int ldo, int n0) {
  for (int i = threadIdx.x; i < 2048; i += NTHR) {
    int m = i >> 6, nn = i & 63;
    float s = red[m * 64 + nn] + red[2048 + m * 64 + nn] +
              red[4096 + m * 64 + nn] + red[6144 + m * 64 + nn];
    cstore(outp + (size_t)m * ldo + n0 + nn, s);
  }
}

// BATCHED gate-partial reduction: NKB loads in flight, then sum
template<int NKB>
__device__ __forceinline__ float gate_sum(const float* p, size_t stride) {
  float v[NKB];
#pragma unroll
  for (int j = 0; j < NKB; j++) v[j] = cload(p + (size_t)j * stride);
  float s = 0.f;
#pragma unroll
  for (int j = 0; j < NKB; j++) s += v[j];
  return s;
}

__global__ __launch_bounds__(NTHR, 2) void seq2seq_kernel(
    const float* __restrict__ embed_in, const float* __restrict__ dec_embed,
    const int* __restrict__ lens,
    const float* __restrict__ Wfw, const float* __restrict__ bfw,
    const float* __restrict__ Wbw, const float* __restrict__ bbw,
    const float* __restrict__ Wd0, const float* __restrict__ bd0,
    const float* __restrict__ Wd1, const float* __restrict__ bd1,
    const float* __restrict__ Wmem, const float* __restrict__ Wq,
    const float* __restrict__ battn, const float* __restrict__ vattn,
    const float* __restrict__ gattn, const float* __restrict__ Wal,
    const float* __restrict__ Wproj, const float* __restrict__ bproj,
    float* __restrict__ out, float* ws) {
  __shared__ float smem[12288];  // 48 KiB: at=[0,4096), red=[4096,12288)
  float* at  = smem;
  float* red = smem + 4096;

  unsigned* arr = (unsigned*)ws;        // [512]
  unsigned* rel = (unsigned*)ws + 512;  // [512*32]
  float* h0     = ws + cfg::F_H0;
  float* c0     = ws + cfg::F_C0;
  float* h1     = ws + cfg::F_H1;
  float* c1     = ws + cfg::F_C1;
  float* attn_s = ws + cfg::F_ATTNS;  // parity stride 16384
  float* vn     = ws + cfg::F_VN;
  float* ctx    = ws + cfg::F_CTX;
  float* p0     = ws + cfg::F_P0;
  float* p1     = ws + cfg::F_P1;
  float* eout   = ws + cfg::F_EOUT;
  float* keysp  = ws + cfg::F_KEYS;

  const int bid = blockIdx.x, tid = threadIdx.x;
  const int wave = tid >> 6, lane = tid & 63;
  unsigned ep = 1;
#define BAR()  do { gbar(ep, arr, rel); ep++; } while (0)
#define BARSEAL() do { __threadfence(); gbar(ep, arr, rel); ep++; __threadfence(); } while (0)

  // ---------------- setup: normalized attention vector ----------------
  if (bid == 0) {
    float s = 0.f;
    for (int u = tid; u < 512; u += NTHR) { float x = vattn[u]; s = fmaf(x, x, s); }
#pragma unroll
    for (int off = 32; off > 0; off >>= 1) s += __shfl_xor(s, off, 64);
    if (lane == 0) at[64 + wave] = s;
    __syncthreads();
    float S = at[64] + at[65] + at[66] + at[67];
    float scale = gattn[0] / sqrtf(S);
    for (int u = tid; u < 512; u += NTHR) vn[u] = vattn[u] * scale;  // plain; sealed below
  }
  BAR();

  // ---------------- bidirectional encoder ----------------
  for (int t = 0; t < 128; t++) {
    // phase A: fw+bw gate GEMMs: 2dir x 32nb x 8kb = 512 blocks, KWIN=128
    {
      int dir = bid >> 8;
      int r = bid & 255;
      int nb = r & 31, kb = r >> 5;
      const float* W = dir ? Wbw : Wfw;
      const float* hs = dir ? h1 : h0;
      stage<128>(at, [&](int m, int kl) -> float {
        int kk = kb * 128 + kl;
        if (kk < 512) {
          int tt = t;
          if (dir) { int len = lens[m]; tt = (t < len) ? (len - 1 - t) : t; }
          return embed_in[((size_t)m * 128 + tt) * 512 + kk];  // read-only cached
        }
        return cload(hs + m * 512 + kk - 512);
      });
      float acc[32];
#pragma unroll
      for (int m = 0; m < 32; m++) acc[m] = 0.f;
      gemm_frag<128, 16>(W, 2048, nb * 64 + lane, true, kb * 128, at, acc);
      red_write(red, acc);
      epi_cstore(red, (dir ? p1 : p0) + (size_t)kb * 65536, 2048, nb * 64);
    }
    BAR();
    // phase B: activations + masked state update + enc_out write (128 blocks)
    if (bid < 128) {
      int dir = bid >> 6;
      int p = (bid & 63) * NTHR + tid;  // 0..16383
      int m = p >> 9, u = p & 511;
      const float* parts = dir ? p1 : p0;
      const float* bias  = dir ? bbw : bfw;
      float* hs = dir ? h1 : h0;
      float* cs = dir ? c1 : c0;
      float g4[4];
#pragma unroll
      for (int g = 0; g < 4; g++)
        g4[g] = bias[g * 512 + u] +
                gate_sum<8>(parts + m * 2048 + g * 512 + u, 65536);
      int len = lens[m];
      bool valid = t < len;
      float co = cload(cs + m * 512 + u);
      float cn = sigm(g4[2] + 1.f) * co + sigm(g4[0]) * tanhft(g4[1]);
      float hn = sigm(g4[3]) * tanhft(cn);
      if (valid) { cstore(cs + m * 512 + u, cn); cstore(hs + m * 512 + u, hn); }
      int tpos = dir ? (valid ? (len - 1 - t) : t) : t;
      eout[((size_t)m * 128 + tpos) * 1024 + dir * 512 + u] = valid ? hn : 0.f;  // sealed
    }
    BAR();
  }

  BARSEAL();  // seal eout + vn

  // ---------------- keys = enc_out @ w_mem (M=4096, N=512, K=1024) ----------------
  {
#pragma unroll 1
    for (int task = bid; task < 1024; task += NBLKS) {
      int mt = task >> 3, nb = task & 7;
      int n0 = nb * 64;
      const float* arow = eout + (size_t)mt * 32 * 1024;
      float acc[32];
#pragma unroll
      for (int m = 0; m < 32; m++) acc[m] = 0.f;
      const int n = n0 + lane;
#pragma unroll 1
      for (int c = 0; c < 8; c++) {
        stage<128>(at, [&](int m, int kl) -> float {
          return arow[(size_t)m * 1024 + c * 128 + kl];
        });
        gemm_frag<128, 16>(Wmem, 512, n, true, c * 128, at, acc);
      }
      red_write(red, acc);
      for (int i = tid; i < 2048; i += NTHR) {
        int m = i >> 6, nn = i & 63;
        float s = red[m * 64 + nn] + red[2048 + m * 64 + nn] +
                  red[4096 + m * 64 + nn] + red[6144 + m * 64 + nn];
        keysp[(size_t)mt * 32 * 512 + (size_t)m * 512 + n0 + nn] = s;  // sealed
      }
    }
  }
  BARSEAL();  // seal keys

  // ---------------- decoder loop (t==128: trailing projection only) ----------------
  for (int t = 0; t <= 128; t++) {
    if (t < 128) {
      // phase A: gates0 GEMM, K=1536 = x(512)|attn(512)|h0(512); 32nb x 16kb, KWIN=96
      {
        int nb = bid & 31, kb = bid >> 5;
        const float* asrc = attn_s + (size_t)((t + 1) & 1) * 16384;  // attn(t-1)
        stage<96>(at, [&](int m, int kl) -> float {
          int kk = kb * 96 + kl;
          if (kk < 512) return dec_embed[((size_t)m * 128 + t) * 512 + kk];
          if (kk < 1024) return cload(asrc + m * 512 + kk - 512);
          return cload(h0 + m * 512 + kk - 1024);
        });
        float acc[32];
#pragma unroll
        for (int m = 0; m < 32; m++) acc[m] = 0.f;
        gemm_frag<96, 12>(Wd0, 2048, nb * 64 + lane, true, kb * 96, at, acc);
        red_write(red, acc);
        epi_cstore(red, p0 + (size_t)kb * 65536, 2048, nb * 64);
      }
      BAR();
    }

    // phase B: act0 (0..63) + zero attn_s[t&1] (64..71)  ||  proj(t-1) (72..353)
    if (t < 128 && bid < 64) {
      int p = bid * NTHR + tid;
      int m = p >> 9, u = p & 511;
      float g4[4];
#pragma unroll
      for (int g = 0; g < 4; g++)
        g4[g] = bd0[g * 512 + u] +
                gate_sum<16>(p0 + m * 2048 + g * 512 + u, 65536);
      float co = cload(c0 + m * 512 + u);
      float cn = sigm(g4[2] + 1.f) * co + sigm(g4[0]) * tanhft(g4[1]);
      float hn = sigm(g4[3]) * tanhft(cn);
      cstore(c0 + m * 512 + u, cn);
      cstore(h0 + m * 512 + u, hn);
    } else if (t < 128 && bid < 72) {
      float* az = attn_s + (size_t)(t & 1) * 16384 + (size_t)(bid - 64) * 2048;
      for (int i = tid; i < 2048; i += NTHR) cstore(az + i, 0.f);
    } else if (bid >= 72 && bid < 354 && t >= 1) {
      // projection of step t-1: out[., t-1, .] += attn(t-1)[Khalf] @ Wproj[Khalf]
      int pb = bid - 72;                 // 0..281
      int nb = pb % 141, kb = pb / 141;  // kb: K-half of 256
      int n0 = nb * 64;
      int tprev = t - 1;
      const float* asrc = attn_s + (size_t)((t + 1) & 1) * 16384;  // attn(t-1)
      const int n = n0 + lane;
      const bool nok = n < 9000;
      float acc[32];
#pragma unroll
      for (int m = 0; m < 32; m++) acc[m] = 0.f;
#pragma unroll 1
      for (int c = 0; c < 2; c++) {
        stage<128>(at, [&](int m, int kl) -> float {
          return cload(asrc + m * 512 + kb * 256 + c * 128 + kl);
        });
        gemm_frag<128, 16>(Wproj, 9000, n, nok, kb * 256 + c * 128, at, acc);
      }
      red_write(red, acc);
      for (int i = tid; i < 2048; i += NTHR) {
        int m = i >> 6, nn = i & 63;
        int nc = n0 + nn;
        if (nc < 9000) {
          float s = red[m * 64 + nn] + red[2048 + m * 64 + nn] +
                    red[4096 + m * 64 + nn] + red[6144 + m * 64 + nn];
          if (kb == 0) s += bproj[nc];
          atomicAdd(out + ((size_t)m * 128 + tprev) * 9000 + nc, s);  // out pre-zeroed
        }
      }
    }
    BAR();

    if (t < 128) {
      // phase C: gates1 GEMM, K=1024 = h0new|h1old; 32nb x 16kb, KWIN=64
      {
        int nb = bid & 31, kb = bid >> 5;
        stage<64>(at, [&](int m, int kl) -> float {
          int kk = kb * 64 + kl;
          return (kk < 512) ? cload(h0 + m * 512 + kk) : cload(h1 + m * 512 + kk - 512);
        });
        float acc[32];
#pragma unroll
        for (int m = 0; m < 32; m++) acc[m] = 0.f;
        gemm_frag<64, 16>(Wd1, 2048, nb * 64 + lane, true, kb * 64, at, acc);
        red_write(red, acc);
        epi_cstore(red, p1 + (size_t)kb * 65536, 2048, nb * 64);
      }
      BAR();

      // phase E: attention, one block per batch row (blocks 0..31)
      if (bid < 32) {
        int b = bid;
        int len = lens[b];
        float* sh_h1v = at;          // 512
        float* sh_qb  = at + 512;    // 512
        float* sh_vnv = at + 1024;   // 512
        float* sh_sc  = at + 1536;   // 128
        float* sh_al  = at + 1664;   // 128
        float* sh_r   = at + 1792;   // 16
        float* redq   = at + 2048;   // 2048 (ends at at[4096))
        // act1 for row b (sole writer; batched partial loads)
#pragma unroll 1
        for (int u = tid; u < 512; u += NTHR) {
          float g4[4];
#pragma unroll
          for (int g = 0; g < 4; g++)
            g4[g] = bd1[g * 512 + u] +
                    gate_sum<16>(p1 + b * 2048 + g * 512 + u, 65536);
          float co = cload(c1 + b * 512 + u);
          float cn = sigm(g4[2] + 1.f) * co + sigm(g4[0]) * tanhft(g4[1]);
          float hn = sigm(g4[3]) * tanhft(cn);
          cstore(c1 + b * 512 + u, cn);
          cstore(h1 + b * 512 + u, hn);
          sh_h1v[u] = hn;
          sh_vnv[u] = vn[u];
        }
        __syncthreads();
        // q = h1n @ w_query
        {
          float4 qa = make_float4(0.f, 0.f, 0.f, 0.f), qb4 = make_float4(0.f, 0.f, 0.f, 0.f);
          const int ua = lane * 4, ub = 256 + lane * 4;
          const float* wqp = Wq + (size_t)(wave * 128) * 512;
#pragma unroll 1
          for (int kk = 0; kk < 128; kk++) {
            float h = sh_h1v[wave * 128 + kk];
            float4 wa = *(const float4*)(wqp + (size_t)kk * 512 + ua);
            float4 wb = *(const float4*)(wqp + (size_t)kk * 512 + ub);
            qa.x = fmaf(h, wa.x, qa.x); qa.y = fmaf(h, wa.y, qa.y);
            qa.z = fmaf(h, wa.z, qa.z); qa.w = fmaf(h, wa.w, qa.w);
            qb4.x = fmaf(h, wb.x, qb4.x); qb4.y = fmaf(h, wb.y, qb4.y);
            qb4.z = fmaf(h, wb.z, qb4.z); qb4.w = fmaf(h, wb.w, qb4.w);
          }
          *(float4*)(redq + wave * 512 + ua) = qa;
          *(float4*)(redq + wave * 512 + ub) = qb4;
        }
        __syncthreads();
        for (int u = tid; u < 512; u += NTHR)
          sh_qb[u] = redq[u] + redq[512 + u] + redq[1024 + u] + redq[1536 + u] + battn[u];
        __syncthreads();
        // scores
#pragma unroll 1
        for (int tt = 0; tt < 32; tt++) {
          int tq = wave * 32 + tt;
          const float* kp = keysp + ((size_t)b * 128 + tq) * 512;
          float s = 0.f;
#pragma unroll
          for (int hh = 0; hh < 2; hh++) {
            int u = lane * 4 + hh * 256;
            float4 k4 = *(const float4*)(kp + u);
            s += sh_vnv[u + 0] * tanhft(k4.x + sh_qb[u + 0]);
            s += sh_vnv[u + 1] * tanhft(k4.y + sh_qb[u + 1]);
            s += sh_vnv[u + 2] * tanhft(k4.z + sh_qb[u + 2]);
            s += sh_vnv[u + 3] * tanhft(k4.w + sh_qb[u + 3]);
          }
#pragma unroll
          for (int off = 32; off > 0; off >>= 1) s += __shfl_xor(s, off, 64);
          if (lane == 0) sh_sc[tq] = (tq < len) ? s : -1e30f;
        }
        __syncthreads();
        // softmax over 128
        {
          float v = (tid < 128) ? sh_sc[tid] : -1e30f;
          float mx = v;
#pragma unroll
          for (int off = 32; off > 0; off >>= 1) mx = fmaxf(mx, __shfl_xor(mx, off, 64));
          if (lane == 0) sh_r[wave] = mx;
          __syncthreads();
          mx = fmaxf(fmaxf(sh_r[0], sh_r[1]), fmaxf(sh_r[2], sh_r[3]));
          float e = (tid < 128 && tid < len) ? __expf(v - mx) : 0.f;
          float sum = e;
#pragma unroll
          for (int off = 32; off > 0; off >>= 1) sum += __shfl_xor(sum, off, 64);
          if (lane == 0) sh_r[8 + wave] = sum;
          __syncthreads();
          float inv = 1.f / (sh_r[8] + sh_r[9] + sh_r[10] + sh_r[11]);
          if (tid < 128) sh_al[tid] = e * inv;
        }
        __syncthreads();
        // context = alpha @ enc_out[b]
        {
          int d = tid * 4;
          float4 acc = make_float4(0.f, 0.f, 0.f, 0.f);
          const float* ep2 = eout + (size_t)b * 128 * 1024 + d;
#pragma unroll 1
          for (int tq = 0; tq < len; tq++) {
            float a = sh_al[tq];
            float4 e4 = *(const float4*)(ep2 + (size_t)tq * 1024);
            acc.x = fmaf(a, e4.x, acc.x); acc.y = fmaf(a, e4.y, acc.y);
            acc.z = fmaf(a, e4.z, acc.z); acc.w = fmaf(a, e4.w, acc.w);
          }
          cstore(ctx + b * 1024 + d + 0, acc.x);
          cstore(ctx + b * 1024 + d + 1, acc.y);
          cstore(ctx + b * 1024 + d + 2, acc.z);
          cstore(ctx + b * 1024 + d + 3, acc.w);
        }
      }
      BAR();

      // phase F: attn(t) = (h1|ctx) @ Wal; 8nb x 16kb = 128 blocks, KWIN=96
      if (bid < 128) {
        int nb = bid & 7, kb = bid >> 3;
        stage<96>(at, [&](int m, int kl) -> float {
          int kk = kb * 96 + kl;
          return (kk < 512) ? cload(h1 + m * 512 + kk) : cload(ctx + m * 1024 + kk - 512);
        });
        float acc[32];
#pragma unroll
        for (int m = 0; m < 32; m++) acc[m] = 0.f;
        gemm_frag<96, 12>(Wal, 512, nb * 64 + lane, true, kb * 96, at, acc);
        red_write(red, acc);
        float* adst = attn_s + (size_t)(t & 1) * 16384;
        for (int i = tid; i < 2048; i += NTHR) {
          int m = i >> 6, nn = i & 63;
          float s = red[m * 64 + nn] + red[2048 + m * 64 + nn] +
                    red[4096 + m * 64 + nn] + red[6144 + m * 64 + nn];
          atomicAdd(adst + (size_t)m * 512 + nb * 64 + nn, s);
        }
      }
      BAR();
    }
  }
#undef BAR
#undef BARSEAL
}

extern "C" void kernel_launch(void* const* d_in, const int* in_sizes, int n_in,
                              void* d_out, int out_size, void* d_ws, size_t ws_size,
                              hipStream_t stream) {
  (void)in_sizes; (void)n_in; (void)ws_size;
  hipMemsetAsync(d_ws, 0, cfg::MEMSET_BYTES, stream);
  hipMemsetAsync(d_out, 0, (size_t)out_size * 4, stream);
  hipLaunchKernelGGL(seq2seq_kernel, dim3(NBLKS), dim3(NTHR), 0, stream,
                     (const float*)d_in[0],   // embed_in
                     (const float*)d_in[1],   // dec_embed
                     (const int*)d_in[2],     // in_seq_len
                     (const float*)d_in[3],   // enc_fw_kernel
                     (const float*)d_in[4],   // enc_fw_bias
                     (const float*)d_in[5],   // enc_bw_kernel
                     (const float*)d_in[6],   // enc_bw_bias
                     (const float*)d_in[7],   // dec_kernel0
                     (const float*)d_in[8],   // dec_bias0
                     (const float*)d_in[9],   // dec_kernel1
                     (const float*)d_in[10],  // dec_bias1
                     (const float*)d_in[11],  // w_mem
                     (const float*)d_in[12],  // w_query
                     (const float*)d_in[13],  // b_attn
                     (const float*)d_in[14],  // v_attn
                     (const float*)d_in[15],  // g_attn
                     (const float*)d_in[16],  // w_attn_layer
                     (const float*)d_in[17],  // w_proj
                     (const float*)d_in[18],  // b_proj
                     (float*)d_out, (float*)d_ws);
}

// Round 10
// 20498.781 us; speedup vs baseline: 3.0285x; 1.4567x over previous
//
#include <hip/hip_runtime.h>
#include <stdint.h>

#define NTHR 256
#define NBLKS 512

namespace cfg {
// ws layout in FLOAT units (identical to round 4/9 — proven)
constexpr size_t F_CELLS = 0;                     // arr[512] u32 + rel[512*32] u32
constexpr size_t F_H0    = 524288;                // [32][512]
constexpr size_t F_C0    = F_H0 + 16384;
constexpr size_t F_H1    = F_C0 + 16384;
constexpr size_t F_C1    = F_H1 + 16384;
constexpr size_t F_ATTNS = F_C1 + 16384;          // [2][32][512] attn vector (parity dbuf)
constexpr size_t F_VN    = F_ATTNS + 32768;       // [512]
constexpr size_t F_CTX   = F_VN + 512;            // [32][1024]
constexpr size_t F_P0    = F_CTX + 32768;         // [16][32][2048] gate partials
constexpr size_t F_P1    = F_P0 + 1048576;        // [16][32][2048]
constexpr size_t F_EOUT  = F_P1 + 1048576;        // [32][128][1024] (write-once)
constexpr size_t F_KEYS  = F_EOUT + 4194304;      // [32][128][512]  (write-once)
constexpr size_t F_TOTAL = F_KEYS + 2097152;      // ~36.2 MB (proven budget)
constexpr size_t MEMSET_BYTES = F_VN * 4;         // cells + states + attn_s
}

__device__ __forceinline__ float sigm(float x)   { return 1.0f / (1.0f + __expf(-x)); }
__device__ __forceinline__ float tanhft(float x) { return 1.0f - 2.0f / (1.0f + __expf(2.0f * x)); }

// 32-bit agent-scope access — the ONLY uncached primitive (R4/R9-proven)
__device__ __forceinline__ float cload(const float* p) {
  return __hip_atomic_load(p, __ATOMIC_RELAXED, __HIP_MEMORY_SCOPE_AGENT);
}
__device__ __forceinline__ void cstore(float* p, float v) {
  __hip_atomic_store(p, v, __ATOMIC_RELAXED, __HIP_MEMORY_SCOPE_AGENT);
}

// checker/broadcast grid barrier (R4-proven, unchanged)
__device__ __forceinline__ void gbar(unsigned ep, unsigned* arr, unsigned* rel) {
  __syncthreads();
  if (blockIdx.x == 0) {
    if (threadIdx.x == 0)
      __hip_atomic_store(arr, ep, __ATOMIC_RELAXED, __HIP_MEMORY_SCOPE_AGENT);
    int s0 = threadIdx.x, s1 = threadIdx.x + 256;
    while (__hip_atomic_load(arr + s0, __ATOMIC_RELAXED, __HIP_MEMORY_SCOPE_AGENT) < ep)
      __builtin_amdgcn_s_sleep(1);
    while (__hip_atomic_load(arr + s1, __ATOMIC_RELAXED, __HIP_MEMORY_SCOPE_AGENT) < ep)
      __builtin_amdgcn_s_sleep(1);
    __syncthreads();
    __hip_atomic_store(rel + (size_t)s0 * 32, ep, __ATOMIC_RELAXED, __HIP_MEMORY_SCOPE_AGENT);
    __hip_atomic_store(rel + (size_t)s1 * 32, ep, __ATOMIC_RELAXED, __HIP_MEMORY_SCOPE_AGENT);
    __syncthreads();
  } else {
    if (threadIdx.x == 0) {
      __hip_atomic_store(arr + blockIdx.x, ep, __ATOMIC_RELAXED, __HIP_MEMORY_SCOPE_AGENT);
      while (__hip_atomic_load(rel + (size_t)blockIdx.x * 32, __ATOMIC_RELAXED,
                               __HIP_MEMORY_SCOPE_AGENT) < ep)
        __builtin_amdgcn_s_sleep(1);
    }
    __syncthreads();
  }
}

// stage A-tile [32][KWIN] into LDS — gather into regs, then write (R9-proven)
template<int KWIN, typename F>
__device__ __forceinline__ void stage(float* at, F&& f) {
  static_assert((32 * KWIN) % NTHR == 0, "tile must tile NTHR");
  constexpr int PER = (32 * KWIN) / NTHR;
  __syncthreads();
  float v[PER];
#pragma unroll
  for (int r = 0; r < PER; r++) {
    int i = threadIdx.x + NTHR * r;
    v[r] = f(i / KWIN, i % KWIN);
  }
#pragma unroll
  for (int r = 0; r < PER; r++) at[threadIdx.x + NTHR * r] = v[r];
  __syncthreads();
}

// GEMM fragment: preload ALL KQ weight rows (<=32, one latency round), then compute
template<int KWIN>
__device__ __forceinline__ void gemm_frag(const float* __restrict__ W, int ldw,
                                          int n, bool nok, int kw0,
                                          const float* at, float* acc) {
  const int wave = threadIdx.x >> 6;
  constexpr int KQ = KWIN / 4;  // 16..32
  const int klo = wave * KQ;
  const float* wp = W + (size_t)(kw0 + klo) * (size_t)ldw + n;
  float w[KQ];
#pragma unroll
  for (int j = 0; j < KQ; j++) w[j] = nok ? wp[(size_t)j * ldw] : 0.f;
#pragma unroll
  for (int jj = 0; jj < KQ; jj += 4) {
    const float* ap = at + klo + jj;
#pragma unroll
    for (int m = 0; m < 32; m++) {
      float4 a = *(const float4*)(ap + m * KWIN);
      acc[m] = fmaf(a.x, w[jj + 0], acc[m]);
      acc[m] = fmaf(a.y, w[jj + 1], acc[m]);
      acc[m] = fmaf(a.z, w[jj + 2], acc[m]);
      acc[m] = fmaf(a.w, w[jj + 3], acc[m]);
    }
  }
}

// red layout [4][32][64] = 8192 floats (proven)
__device__ __forceinline__ void red_write(float* red, const float* acc) {
  const int wave = threadIdx.x >> 6, lane = threadIdx.x & 63;
  __syncthreads();
#pragma unroll
  for (int m = 0; m < 32; m++) red[(wave * 32 + m) * 64 + lane] = acc[m];
  __syncthreads();
}

__device__ __forceinline__ void epi_cstore(const float* red, float* outp, int ldo, int n0) {
  for (int i = threadIdx.x; i < 2048; i += NTHR) {
    int m = i >> 6, nn = i & 63;
    float s = red[m * 64 + nn] + red[2048 + m * 64 + nn] +
              red[4096 + m * 64 + nn] + red[6144 + m * 64 + nn];
    cstore(outp + (size_t)m * ldo + n0 + nn, s);
  }
}

// ALL 4 gates x NKB partial loads issued back-to-back (one latency round), then sum
template<int NKB>
__device__ __forceinline__ void gate_sum4(const float* base, float g4[4]) {
  float v[4][NKB];
#pragma unroll
  for (int g = 0; g < 4; g++) {
    const float* p = base + g * 512;
#pragma unroll
    for (int j = 0; j < NKB; j++) v[g][j] = cload(p + (size_t)j * 65536);
  }
#pragma unroll
  for (int g = 0; g < 4; g++) {
    float s = 0.f;
#pragma unroll
    for (int j = 0; j < NKB; j++) s += v[g][j];
    g4[g] = s;
  }
}

__global__ __launch_bounds__(NTHR, 2) void seq2seq_kernel(
    const float* __restrict__ embed_in, const float* __restrict__ dec_embed,
    const int* __restrict__ lens,
    const float* __restrict__ Wfw, const float* __restrict__ bfw,
    const float* __restrict__ Wbw, const float* __restrict__ bbw,
    const float* __restrict__ Wd0, const float* __restrict__ bd0,
    const float* __restrict__ Wd1, const float* __restrict__ bd1,
    const float* __restrict__ Wmem, const float* __restrict__ Wq,
    const float* __restrict__ battn, const float* __restrict__ vattn,
    const float* __restrict__ gattn, const float* __restrict__ Wal,
    const float* __restrict__ Wproj, const float* __restrict__ bproj,
    float* __restrict__ out, float* ws) {
  __shared__ float smem[12288];  // 48 KiB: at=[0,4096), red=[4096,12288)
  float* at  = smem;
  float* red = smem + 4096;

  unsigned* arr = (unsigned*)ws;        // [512]
  unsigned* rel = (unsigned*)ws + 512;  // [512*32]
  float* h0     = ws + cfg::F_H0;
  float* c0     = ws + cfg::F_C0;
  float* h1     = ws + cfg::F_H1;
  float* c1     = ws + cfg::F_C1;
  float* attn_s = ws + cfg::F_ATTNS;  // parity stride 16384
  float* vn     = ws + cfg::F_VN;
  float* ctx    = ws + cfg::F_CTX;
  float* p0     = ws + cfg::F_P0;
  float* p1     = ws + cfg::F_P1;
  float* eout   = ws + cfg::F_EOUT;
  float* keysp  = ws + cfg::F_KEYS;

  const int bid = blockIdx.x, tid = threadIdx.x;
  const int wave = tid >> 6, lane = tid & 63;
  unsigned ep = 1;
#define BAR()  do { gbar(ep, arr, rel); ep++; } while (0)
#define BARSEAL() do { __threadfence(); gbar(ep, arr, rel); ep++; __threadfence(); } while (0)

  // ---------------- setup: normalized attention vector ----------------
  if (bid == 0) {
    float s = 0.f;
    for (int u = tid; u < 512; u += NTHR) { float x = vattn[u]; s = fmaf(x, x, s); }
#pragma unroll
    for (int off = 32; off > 0; off >>= 1) s += __shfl_xor(s, off, 64);
    if (lane == 0) at[64 + wave] = s;
    __syncthreads();
    float S = at[64] + at[65] + at[66] + at[67];
    float scale = gattn[0] / sqrtf(S);
    for (int u = tid; u < 512; u += NTHR) vn[u] = vattn[u] * scale;  // plain; sealed below
  }
  BAR();

  // ---------------- bidirectional encoder ----------------
  for (int t = 0; t < 128; t++) {
    // phase A: fw+bw gate GEMMs: 2dir x 32nb x 8kb = 512 blocks, KWIN=128
    {
      int dir = bid >> 8;
      int r = bid & 255;
      int nb = r & 31, kb = r >> 5;
      const float* W = dir ? Wbw : Wfw;
      const float* hs = dir ? h1 : h0;
      stage<128>(at, [&](int m, int kl) -> float {
        int kk = kb * 128 + kl;
        if (kk < 512) {
          int tt = t;
          if (dir) { int len = lens[m]; tt = (t < len) ? (len - 1 - t) : t; }
          return embed_in[((size_t)m * 128 + tt) * 512 + kk];  // read-only cached
        }
        return cload(hs + m * 512 + kk - 512);
      });
      float acc[32];
#pragma unroll
      for (int m = 0; m < 32; m++) acc[m] = 0.f;
      gemm_frag<128>(W, 2048, nb * 64 + lane, true, kb * 128, at, acc);
      red_write(red, acc);
      epi_cstore(red, (dir ? p1 : p0) + (size_t)kb * 65536, 2048, nb * 64);
    }
    BAR();
    // phase B: activations + masked state update + enc_out write (128 blocks)
    if (bid < 128) {
      int dir = bid >> 6;
      int p = (bid & 63) * NTHR + tid;  // 0..16383
      int m = p >> 9, u = p & 511;
      const float* parts = dir ? p1 : p0;
      const float* bias  = dir ? bbw : bfw;
      float* hs = dir ? h1 : h0;
      float* cs = dir ? c1 : c0;
      float g4[4];
      gate_sum4<8>(parts + m * 2048 + u, g4);
#pragma unroll
      for (int g = 0; g < 4; g++) g4[g] += bias[g * 512 + u];
      int len = lens[m];
      bool valid = t < len;
      float co = cload(cs + m * 512 + u);
      float cn = sigm(g4[2] + 1.f) * co + sigm(g4[0]) * tanhft(g4[1]);
      float hn = sigm(g4[3]) * tanhft(cn);
      if (valid) { cstore(cs + m * 512 + u, cn); cstore(hs + m * 512 + u, hn); }
      int tpos = dir ? (valid ? (len - 1 - t) : t) : t;
      eout[((size_t)m * 128 + tpos) * 1024 + dir * 512 + u] = valid ? hn : 0.f;  // sealed
    }
    BAR();
  }

  BARSEAL();  // seal eout + vn

  // ---------------- keys = enc_out @ w_mem (M=4096, N=512, K=1024) ----------------
  {
#pragma unroll 1
    for (int task = bid; task < 1024; task += NBLKS) {
      int mt = task >> 3, nb = task & 7;
      int n0 = nb * 64;
      const float* arow = eout + (size_t)mt * 32 * 1024;
      float acc[32];
#pragma unroll
      for (int m = 0; m < 32; m++) acc[m] = 0.f;
      const int n = n0 + lane;
#pragma unroll 1
      for (int c = 0; c < 8; c++) {
        stage<128>(at, [&](int m, int kl) -> float {
          return arow[(size_t)m * 1024 + c * 128 + kl];
        });
        gemm_frag<128>(Wmem, 512, n, true, c * 128, at, acc);
      }
      red_write(red, acc);
      for (int i = tid; i < 2048; i += NTHR) {
        int m = i >> 6, nn = i & 63;
        float s = red[m * 64 + nn] + red[2048 + m * 64 + nn] +
                  red[4096 + m * 64 + nn] + red[6144 + m * 64 + nn];
        keysp[(size_t)mt * 32 * 512 + (size_t)m * 512 + n0 + nn] = s;  // sealed
      }
    }
  }
  BARSEAL();  // seal keys

  // ---------------- decoder loop (t==128: trailing projection only) ----------------
  for (int t = 0; t <= 128; t++) {
    if (t < 128) {
      // phase A: gates0 GEMM, K=1536 = x(512)|attn(512)|h0(512); 32nb x 16kb, KWIN=96
      {
        int nb = bid & 31, kb = bid >> 5;
        const float* asrc = attn_s + (size_t)((t + 1) & 1) * 16384;  // attn(t-1)
        stage<96>(at, [&](int m, int kl) -> float {
          int kk = kb * 96 + kl;
          if (kk < 512) return dec_embed[((size_t)m * 128 + t) * 512 + kk];
          if (kk < 1024) return cload(asrc + m * 512 + kk - 512);
          return cload(h0 + m * 512 + kk - 1024);
        });
        float acc[32];
#pragma unroll
        for (int m = 0; m < 32; m++) acc[m] = 0.f;
        gemm_frag<96>(Wd0, 2048, nb * 64 + lane, true, kb * 96, at, acc);
        red_write(red, acc);
        epi_cstore(red, p0 + (size_t)kb * 65536, 2048, nb * 64);
      }
      BAR();
    }

    // phase B: act0 (0..63) + zero attn_s[t&1] (64..71)  ||  proj(t-1) (72..353)
    if (t < 128 && bid < 64) {
      int p = bid * NTHR + tid;
      int m = p >> 9, u = p & 511;
      float g4[4];
      gate_sum4<16>(p0 + m * 2048 + u, g4);
#pragma unroll
      for (int g = 0; g < 4; g++) g4[g] += bd0[g * 512 + u];
      float co = cload(c0 + m * 512 + u);
      float cn = sigm(g4[2] + 1.f) * co + sigm(g4[0]) * tanhft(g4[1]);
      float hn = sigm(g4[3]) * tanhft(cn);
      cstore(c0 + m * 512 + u, cn);
      cstore(h0 + m * 512 + u, hn);
    } else if (t < 128 && bid < 72) {
      float* az = attn_s + (size_t)(t & 1) * 16384 + (size_t)(bid - 64) * 2048;
      for (int i = tid; i < 2048; i += NTHR) cstore(az + i, 0.f);
    } else if (bid >= 72 && bid < 354 && t >= 1) {
      // projection of step t-1: out[., t-1, .] += attn(t-1)[Khalf] @ Wproj[Khalf]
      int pb = bid - 72;                 // 0..281
      int nb = pb % 141, kb = pb / 141;  // kb: K-half of 256
      int n0 = nb * 64;
      int tprev = t - 1;
      const float* asrc = attn_s + (size_t)((t + 1) & 1) * 16384;  // attn(t-1)
      const int n = n0 + lane;
      const bool nok = n < 9000;
      float acc[32];
#pragma unroll
      for (int m = 0; m < 32; m++) acc[m] = 0.f;
#pragma unroll 1
      for (int c = 0; c < 2; c++) {
        stage<128>(at, [&](int m, int kl) -> float {
          return cload(asrc + m * 512 + kb * 256 + c * 128 + kl);
        });
        gemm_frag<128>(Wproj, 9000, n, nok, kb * 256 + c * 128, at, acc);
      }
      red_write(red, acc);
      for (int i = tid; i < 2048; i += NTHR) {
        int m = i >> 6, nn = i & 63;
        int nc = n0 + nn;
        if (nc < 9000) {
          float s = red[m * 64 + nn] + red[2048 + m * 64 + nn] +
                    red[4096 + m * 64 + nn] + red[6144 + m * 64 + nn];
          if (kb == 0) s += bproj[nc];
          atomicAdd(out + ((size_t)m * 128 + tprev) * 9000 + nc, s);  // out pre-zeroed
        }
      }
    }
    BAR();

    if (t < 128) {
      // phase C: gates1 GEMM, K=1024 = h0new|h1old; 32nb x 16kb, KWIN=64
      {
        int nb = bid & 31, kb = bid >> 5;
        stage<64>(at, [&](int m, int kl) -> float {
          int kk = kb * 64 + kl;
          return (kk < 512) ? cload(h0 + m * 512 + kk) : cload(h1 + m * 512 + kk - 512);
        });
        float acc[32];
#pragma unroll
        for (int m = 0; m < 32; m++) acc[m] = 0.f;
        gemm_frag<64>(Wd1, 2048, nb * 64 + lane, true, kb * 64, at, acc);
        red_write(red, acc);
        epi_cstore(red, p1 + (size_t)kb * 65536, 2048, nb * 64);
      }
      BAR();

      // phase E: attention, one block per batch row (blocks 0..31)
      if (bid < 32) {
        int b = bid;
        int len = lens[b];
        float* sh_h1v = at;          // 512
        float* sh_qb  = at + 512;    // 512
        float* sh_vnv = at + 1024;   // 512
        float* sh_sc  = at + 1536;   // 128
        float* sh_al  = at + 1664;   // 128
        float* sh_r   = at + 1792;   // 16
        float* redq   = at + 2048;   // 2048 (ends at at[4096))
        // act1 for row b (sole writer; one batched latency round per u-iter)
#pragma unroll 1
        for (int u = tid; u < 512; u += NTHR) {
          float g4[4];
          gate_sum4<16>(p1 + b * 2048 + u, g4);
#pragma unroll
          for (int g = 0; g < 4; g++) g4[g] += bd1[g * 512 + u];
          float co = cload(c1 + b * 512 + u);
          float cn = sigm(g4[2] + 1.f) * co + sigm(g4[0]) * tanhft(g4[1]);
          float hn = sigm(g4[3]) * tanhft(cn);
          cstore(c1 + b * 512 + u, cn);
          cstore(h1 + b * 512 + u, hn);
          sh_h1v[u] = hn;
          sh_vnv[u] = vn[u];
        }
        __syncthreads();
        // q = h1n @ w_query — batched x8 (16 loads in flight)
        {
          float4 qa = make_float4(0.f, 0.f, 0.f, 0.f), qb4 = make_float4(0.f, 0.f, 0.f, 0.f);
          const int ua = lane * 4, ub = 256 + lane * 4;
          const float* wqp = Wq + (size_t)(wave * 128) * 512;
#pragma unroll 1
          for (int kk = 0; kk < 128; kk += 8) {
            float4 wa[8], wb[8];
#pragma unroll
            for (int j = 0; j < 8; j++) {
              wa[j] = *(const float4*)(wqp + (size_t)(kk + j) * 512 + ua);
              wb[j] = *(const float4*)(wqp + (size_t)(kk + j) * 512 + ub);
            }
#pragma unroll
            for (int j = 0; j < 8; j++) {
              float h = sh_h1v[wave * 128 + kk + j];
              qa.x = fmaf(h, wa[j].x, qa.x); qa.y = fmaf(h, wa[j].y, qa.y);
              qa.z = fmaf(h, wa[j].z, qa.z); qa.w = fmaf(h, wa[j].w, qa.w);
              qb4.x = fmaf(h, wb[j].x, qb4.x); qb4.y = fmaf(h, wb[j].y, qb4.y);
              qb4.z = fmaf(h, wb[j].z, qb4.z); qb4.w = fmaf(h, wb[j].w, qb4.w);
            }
          }
          *(float4*)(redq + wave * 512 + ua) = qa;
          *(float4*)(redq + wave * 512 + ub) = qb4;
        }
        __syncthreads();
        for (int u = tid; u < 512; u += NTHR)
          sh_qb[u] = redq[u] + redq[512 + u] + redq[1024 + u] + redq[1536 + u] + battn[u];
        __syncthreads();
        // scores — batched x4 (8 loads in flight)
#pragma unroll 1
        for (int tt = 0; tt < 32; tt += 4) {
          float4 kv[4][2];
#pragma unroll
          for (int j = 0; j < 4; j++) {
            const float* kp = keysp + ((size_t)b * 128 + wave * 32 + tt + j) * 512;
            kv[j][0] = *(const float4*)(kp + lane * 4);
            kv[j][1] = *(const float4*)(kp + lane * 4 + 256);
          }
#pragma unroll
          for (int j = 0; j < 4; j++) {
            int tq = wave * 32 + tt + j;
            float s = 0.f;
#pragma unroll
            for (int hh = 0; hh < 2; hh++) {
              int u = lane * 4 + hh * 256;
              float4 k4 = kv[j][hh];
              s += sh_vnv[u + 0] * tanhft(k4.x + sh_qb[u + 0]);
              s += sh_vnv[u + 1] * tanhft(k4.y + sh_qb[u + 1]);
              s += sh_vnv[u + 2] * tanhft(k4.z + sh_qb[u + 2]);
              s += sh_vnv[u + 3] * tanhft(k4.w + sh_qb[u + 3]);
            }
#pragma unroll
            for (int off = 32; off > 0; off >>= 1) s += __shfl_xor(s, off, 64);
            if (lane == 0) sh_sc[tq] = (tq < len) ? s : -1e30f;
          }
        }
        __syncthreads();
        // softmax over 128
        {
          float v = (tid < 128) ? sh_sc[tid] : -1e30f;
          float mx = v;
#pragma unroll
          for (int off = 32; off > 0; off >>= 1) mx = fmaxf(mx, __shfl_xor(mx, off, 64));
          if (lane == 0) sh_r[wave] = mx;
          __syncthreads();
          mx = fmaxf(fmaxf(sh_r[0], sh_r[1]), fmaxf(sh_r[2], sh_r[3]));
          float e = (tid < 128 && tid < len) ? __expf(v - mx) : 0.f;
          float sum = e;
#pragma unroll
          for (int off = 32; off > 0; off >>= 1) sum += __shfl_xor(sum, off, 64);
          if (lane == 0) sh_r[8 + wave] = sum;
          __syncthreads();
          float inv = 1.f / (sh_r[8] + sh_r[9] + sh_r[10] + sh_r[11]);
          if (tid < 128) sh_al[tid] = e * inv;   // 0 for masked entries
        }
        __syncthreads();
        // context = alpha @ enc_out[b] — batched x8; masked rows have alpha=0
        {
          int d = tid * 4;
          float4 acc = make_float4(0.f, 0.f, 0.f, 0.f);
          const float* ep2 = eout + (size_t)b * 128 * 1024 + d;
#pragma unroll 1
          for (int tq0 = 0; tq0 < 128; tq0 += 8) {
            float4 e4[8];
#pragma unroll
            for (int j = 0; j < 8; j++)
              e4[j] = *(const float4*)(ep2 + (size_t)(tq0 + j) * 1024);
#pragma unroll
            for (int j = 0; j < 8; j++) {
              float a = sh_al[tq0 + j];
              acc.x = fmaf(a, e4[j].x, acc.x); acc.y = fmaf(a, e4[j].y, acc.y);
              acc.z = fmaf(a, e4[j].z, acc.z); acc.w = fmaf(a, e4[j].w, acc.w);
            }
          }
          cstore(ctx + b * 1024 + d + 0, acc.x);
          cstore(ctx + b * 1024 + d + 1, acc.y);
          cstore(ctx + b * 1024 + d + 2, acc.z);
          cstore(ctx + b * 1024 + d + 3, acc.w);
        }
      }
      BAR();

      // phase F: attn(t) = (h1|ctx) @ Wal; 8nb x 16kb = 128 blocks, KWIN=96
      if (bid < 128) {
        int nb = bid & 7, kb = bid >> 3;
        stage<96>(at, [&](int m, int kl) -> float {
          int kk = kb * 96 + kl;
          return (kk < 512) ? cload(h1 + m * 512 + kk) : cload(ctx + m * 1024 + kk - 512);
        });
        float acc[32];
#pragma unroll
        for (int m = 0; m < 32; m++) acc[m] = 0.f;
        gemm_frag<96>(Wal, 512, nb * 64 + lane, true, kb * 96, at, acc);
        red_write(red, acc);
        float* adst = attn_s + (size_t)(t & 1) * 16384;
        for (int i = tid; i < 2048; i += NTHR) {
          int m = i >> 6, nn = i & 63;
          float s = red[m * 64 + nn] + red[2048 + m * 64 + nn] +
                    red[4096 + m * 64 + nn] + red[6144 + m * 64 + nn];
          atomicAdd(adst + (size_t)m * 512 + nb * 64 + nn, s);
        }
      }
      BAR();
    }
  }
#undef BAR
#undef BARSEAL
}

extern "C" void kernel_launch(void* const* d_in, const int* in_sizes, int n_in,
                              void* d_out, int out_size, void* d_ws, size_t ws_size,
                              hipStream_t stream) {
  (void)in_sizes; (void)n_in; (void)ws_size;
  hipMemsetAsync(d_ws, 0, cfg::MEMSET_BYTES, stream);
  hipMemsetAsync(d_out, 0, (size_t)out_size * 4, stream);
  hipLaunchKernelGGL(seq2seq_kernel, dim3(NBLKS), dim3(NTHR), 0, stream,
                     (const float*)d_in[0],   // embed_in
                     (const float*)d_in[1],   // dec_embed
                     (const int*)d_in[2],     // in_seq_len
                     (const float*)d_in[3],   // enc_fw_kernel
                     (const float*)d_in[4],   // enc_fw_bias
                     (const float*)d_in[5],   // enc_bw_kernel
                     (const float*)d_in[6],   // enc_bw_bias
                     (const float*)d_in[7],   // dec_kernel0
                     (const float*)d_in[8],   // dec_bias0
                     (const float*)d_in[9],   // dec_kernel1
                     (const float*)d_in[10],  // dec_bias1
                     (const float*)d_in[11],  // w_mem
                     (const float*)d_in[12],  // w_query
                     (const float*)d_in[13],  // b_attn
                     (const float*)d_in[14],  // v_attn
                     (const float*)d_in[15],  // g_attn
                     (const float*)d_in[16],  // w_attn_layer
                     (const float*)d_in[17],  // w_proj
                     (const float*)d_in[18],  // b_proj
                     (float*)d_out, (float*)d_ws);
}